// Round 1
// baseline (3651.250 us; speedup 1.0000x reference)
//
#include <hip/hip_runtime.h>

typedef unsigned short u16;
typedef unsigned int u32;
typedef __attribute__((ext_vector_type(8))) short bf16x8;
typedef __attribute__((ext_vector_type(4))) float f32x4;

#define SB 16
#define SS 2048
#define SD 256
#define CC 16            // chunk length
#define NCH (SS / CC)    // 128 chunks
#define KAPPA 4.8828125e-6f   // 0.01 * 2/(16*256)
#define RP 24            // u16 pitch of transposed 16x16 publish tiles

__device__ __forceinline__ u16 f2bf(float f) {
  u32 u = __float_as_uint(f);
  u = (u + 0x7FFFu + ((u >> 16) & 1u)) >> 16;
  return (u16)u;
}
__device__ __forceinline__ float bf2f(u16 u) { return __uint_as_float((u32)u << 16); }

__device__ __forceinline__ bf16x8 ldfrag(const u16* p) {
  union { uint4 u; bf16x8 f; } cv;
  cv.u = *(const uint4*)p;
  return cv.f;
}
__device__ __forceinline__ bf16x8 asfrag(uint4 q) {
  union { uint4 u; bf16x8 f; } cv;
  cv.u = q;
  return cv.f;
}
__device__ __forceinline__ f32x4 mfma16(bf16x8 a, bf16x8 b, f32x4 c) {
  return __builtin_amdgcn_mfma_f32_16x16x32_bf16(a, b, c, 0, 0, 0);
}

// Raw workgroup barrier: drains LDS ops (cross-wave publish ordering) but
// deliberately does NOT drain vmcnt -- prefetched global loads stay in
// flight across the barrier (__syncthreads would force vmcnt(0)).
__device__ __forceinline__ void wg_barrier() {
  asm volatile("s_waitcnt lgkmcnt(0)" ::: "memory");
  __builtin_amdgcn_s_barrier();
}

// ---------------- prep: train/state (bf16 [t][b][d]) + trainT ([t][d][b]) ----
__global__ __launch_bounds__(256) void prep_kernel(
    const float* __restrict__ x, const float* __restrict__ noise,
    const float* __restrict__ a1,
    u16* __restrict__ train, u16* __restrict__ state, u16* __restrict__ trainT) {
  size_t i4 = (size_t)blockIdx.x * 256 + threadIdx.x;
  size_t base = i4 * 4;
  int d = (int)(base & 255);
  int t = (int)((base >> 8) & 2047);
  int b = (int)(base >> 19);
  float4 xv = *(const float4*)(x + base);
  float4 nv = *(const float4*)(noise + base);
  float4 av = *(const float4*)(a1 + d);
  float m0 = tanhf(av.x * xv.x);
  float m1 = tanhf(av.y * xv.y);
  float m2 = tanhf(av.z * xv.z);
  float m3 = tanhf(av.w * xv.w);
  size_t dst = ((size_t)t * SB + b) * SD + d;
  ushort4 tr, st;
  tr.x = f2bf(m0 + nv.x); tr.y = f2bf(m1 + nv.y);
  tr.z = f2bf(m2 + nv.z); tr.w = f2bf(m3 + nv.w);
  st.x = f2bf(m0); st.y = f2bf(m1); st.z = f2bf(m2); st.w = f2bf(m3);
  *(ushort4*)(train + dst) = tr;
  *(ushort4*)(state + dst) = st;
  size_t tb = ((size_t)t * SD + d) * SB + b;   // trainT[t][d][b]
  trainT[tb + 0 * SB] = tr.x;
  trainT[tb + 1 * SB] = tr.y;
  trainT[tb + 2 * SB] = tr.z;
  trainT[tb + 3 * SB] = tr.w;
}

// ---------------- gram2: AG[c][t][sp][16][32], LbG likewise (zero-filled) ----
__global__ __launch_bounds__(256) void gram2_kernel(
    const u16* __restrict__ tr, const u16* __restrict__ st,
    u16* __restrict__ AG, u16* __restrict__ LbG) {
  const int cb = blockIdx.x;        // c*16 + t
  const int c = cb >> 4, t = cb & 15;
  const int tid = threadIdx.x, lane = tid & 63, wv = tid >> 6;
  const int lr = lane & 15, lq = lane >> 4;
  const size_t Tt = (size_t)cb;
  bf16x8 trF[8], stF[8];
#pragma unroll
  for (int k = 0; k < 8; ++k) {
    trF[k] = ldfrag(tr + (Tt * 16 + lr) * 256 + k * 32 + lq * 8);
    stF[k] = ldfrag(st + (Tt * 16 + lr) * 256 + k * 32 + lq * 8);
  }
  for (int ii = 0; ii < 2; ++ii) {
    const int sp = wv + ii * 4;
    u16* dA = AG + ((size_t)cb * 8 + sp) * 512;
    u16* dL = LbG + ((size_t)cb * 8 + sp) * 512;
#pragma unroll
    for (int h = 0; h < 2; ++h) {
      const int s = 2 * sp + h;
      f32x4 accA = {0.f, 0.f, 0.f, 0.f}, accL = {0.f, 0.f, 0.f, 0.f};
      if (s <= t) {
        const u16* bsrc = tr + ((size_t)(c * 16 + s) * 16 + lr) * 256 + lq * 8;
#pragma unroll
        for (int k = 0; k < 8; ++k) {
          bf16x8 bk = ldfrag(bsrc + k * 32);
          if (s < t) accA = mfma16(trF[k], bk, accA);
          accL = mfma16(stF[k], bk, accL);
        }
      }
#pragma unroll
      for (int r = 0; r < 4; ++r) {
        int idx = (lq * 4 + r) * 32 + h * 16 + lr;
        dA[idx] = (s < t) ? f2bf(accA[r]) : (u16)0;
        dL[idx] = (s <= t) ? f2bf(accL[r]) : (u16)0;
      }
    }
  }
}

// ---------------- ff path: out = u .* (v @ Wp^T) + prev(out)  --------------
__global__ __launch_bounds__(256) void ff_kernel(
    const float* __restrict__ x, const float* __restrict__ a2,
    const float* __restrict__ Wp, const float* __restrict__ ffa,
    const float* __restrict__ ffb, const float* __restrict__ ffg_,
    const float* __restrict__ ffe_, float* __restrict__ out) {
  __shared__ float As[32][68];
  __shared__ float Bs[32][68];
  const int tid = threadIdx.x;
  const int gm0 = blockIdx.x * 64;
  const int gn0 = blockIdx.y * 64;
  const int tm = tid & 15, tn = tid >> 4;
  const int lr = tid & 63;
  const int lq = tid >> 6;
  float acc[4][4];
#pragma unroll
  for (int i = 0; i < 4; i++)
#pragma unroll
    for (int j = 0; j < 4; j++) acc[i][j] = 0.f;

  for (int k0 = 0; k0 < 256; k0 += 32) {
    {
      const float* xp = x + (size_t)(gm0 + lr) * 256 + k0 + lq * 8;
      float4 v0 = *(const float4*)(xp);
      float4 v1 = *(const float4*)(xp + 4);
      const float* ap = a2 + k0 + lq * 8;
      float4 a0 = *(const float4*)(ap);
      float4 a1v = *(const float4*)(ap + 4);
      As[lq * 8 + 0][lr] = tanhf(a0.x * v0.x);
      As[lq * 8 + 1][lr] = tanhf(a0.y * v0.y);
      As[lq * 8 + 2][lr] = tanhf(a0.z * v0.z);
      As[lq * 8 + 3][lr] = tanhf(a0.w * v0.w);
      As[lq * 8 + 4][lr] = tanhf(a1v.x * v1.x);
      As[lq * 8 + 5][lr] = tanhf(a1v.y * v1.y);
      As[lq * 8 + 6][lr] = tanhf(a1v.z * v1.z);
      As[lq * 8 + 7][lr] = tanhf(a1v.w * v1.w);
      const float* wp = Wp + (size_t)(gn0 + lr) * 256 + k0 + lq * 8;
      float4 w0 = *(const float4*)(wp);
      float4 w1 = *(const float4*)(wp + 4);
      Bs[lq * 8 + 0][lr] = w0.x; Bs[lq * 8 + 1][lr] = w0.y;
      Bs[lq * 8 + 2][lr] = w0.z; Bs[lq * 8 + 3][lr] = w0.w;
      Bs[lq * 8 + 4][lr] = w1.x; Bs[lq * 8 + 5][lr] = w1.y;
      Bs[lq * 8 + 6][lr] = w1.z; Bs[lq * 8 + 7][lr] = w1.w;
    }
    __syncthreads();
#pragma unroll
    for (int k = 0; k < 32; ++k) {
      float4 av4 = *(const float4*)&As[k][tm * 4];
      float4 bv4 = *(const float4*)&Bs[k][tn * 4];
      float a[4] = {av4.x, av4.y, av4.z, av4.w};
      float b[4] = {bv4.x, bv4.y, bv4.z, bv4.w};
#pragma unroll
      for (int i = 0; i < 4; i++)
#pragma unroll
        for (int j = 0; j < 4; j++) acc[i][j] += a[i] * b[j];
    }
    __syncthreads();
  }
  const float ga = ffg_[0], et = ffe_[0];
#pragma unroll
  for (int ii = 0; ii < 4; ++ii) {
    int row = gm0 + tm * 4 + ii;
    int col = gn0 + tn * 4;
    float4 xv = *(const float4*)(x + (size_t)row * 256 + col);
    float4 prev = *(const float4*)(out + (size_t)row * 256 + col);
    float4 fa = *(const float4*)(ffa + col);
    float4 fb = *(const float4*)(ffb + col);
    float4 a2v = *(const float4*)(a2 + col);
    float xs[4] = {xv.x, xv.y, xv.z, xv.w};
    float fas[4] = {fa.x, fa.y, fa.z, fa.w};
    float fbs[4] = {fb.x, fb.y, fb.z, fb.w};
    float a2s[4] = {a2v.x, a2v.y, a2v.z, a2v.w};
    float pv[4] = {prev.x, prev.y, prev.z, prev.w};
    float res[4];
#pragma unroll
    for (int j = 0; j < 4; ++j) {
      float v = tanhf(a2s[j] * xs[j]);
      float z = fas[j] * v;
      float gelu = 0.5f * z * (1.0f + erff(z * 0.70710678118654752f));
      float u = ga * gelu + et * sinf(fbs[j] * v);
      res[j] = u * acc[ii][j] + pv[j];
    }
    float4 o; o.x = res[0]; o.y = res[1]; o.z = res[2]; o.w = res[3];
    *(float4*)(out + (size_t)row * 256 + col) = o;
  }
}

// ---------------- scan: 16 WGs x 512 thr; wave w owns t=w and t=w+8 --------
// Software-pipelined: every global load for chunk c is issued >=1 phase
// before its consumer, and (via raw barriers) stays in flight across
// barriers.  Triangular AG/LbG loads skip stored-zero blocks.
__global__ __launch_bounds__(512, 1) void scan_kernel(
    const u16* __restrict__ tr, const u16* __restrict__ st,
    const u16* __restrict__ trT, const u16* __restrict__ AG,
    const u16* __restrict__ LbG, const float* __restrict__ Wttt,
    float* __restrict__ out) {
  __shared__ u16 RpL[CC][16 * RP];   // bf16(rhs) transposed [d1][b]
  __shared__ u16 Y1L[CC][16 * RP];
  __shared__ u16 DpL[CC][16 * RP];
  __shared__ u16 WbL[16][268];       // bf16 W block [d1][d], pitch 268
  __shared__ float WfL[16][268];     // f32 master

  const int tid = threadIdx.x;
  const int lane = tid & 63;
  const int w = tid >> 6;            // wave 0..7
  const int d1b = blockIdx.x;
  const int lr = lane & 15;
  const int lq = lane >> 4;
  // triangular sp-block counts (each sp covers s in {2sp, 2sp+1})
  const int nA0 = (w + 1) >> 1;        // t=w:   blocks with s<t   (<=4)
  const int nA1 = (w + 9) >> 1;        // t=w+8: blocks with s<t   (4..8)
  const int nL0 = (w >> 1) + 1;        // t=w:   blocks with s<=t  (<=4)
  const int nL1 = ((w + 8) >> 1) + 1;  // t=w+8: blocks with s<=t  (5..8)

  for (int i = tid; i < 16 * 256; i += 512) {
    int r = i >> 8, d = i & 255;
    float wv_ = Wttt[(size_t)(d1b * 16 + r) * 256 + d];
    WfL[r][d] = wv_;
    WbL[r][d] = f2bf(wv_);
  }

  uint4 trR[2][8], stR[2][8];
  uint4 agRa[4], agRb[8];
  u16 subR[2][4];

  // ---- prologue: prefetch all chunk-0 inputs ----
#pragma unroll
  for (int u = 0; u < 2; ++u) {
    const size_t T = (size_t)(w + 8 * u);
    const u16* trt = tr + (T * 16 + lr) * 256 + lq * 8;
    const u16* stt = st + (T * 16 + lr) * 256 + lq * 8;
#pragma unroll
    for (int k = 0; k < 8; ++k) {
      trR[u][k] = *(const uint4*)(trt + k * 32);
      stR[u][k] = *(const uint4*)(stt + k * 32);
    }
#pragma unroll
    for (int r = 0; r < 4; ++r)
      subR[u][r] = st[(T * 16 + lq * 4 + r) * 256 + d1b * 16 + lr];
  }
  {
    const u16* ag0 = AG + ((size_t)w * 8) * 512 + lr * 32 + lq * 8;
    const u16* ag1 = ag0 + 8ull * 8 * 512;
#pragma unroll
    for (int sp = 0; sp < 4; ++sp)
      if (sp < nA0) agRa[sp] = *(const uint4*)(ag0 + sp * 512);
#pragma unroll
    for (int sp = 0; sp < 8; ++sp)
      if (sp < nA1) agRb[sp] = *(const uint4*)(ag1 + sp * 512);
  }

  wg_barrier();  // W tiles ready

  for (int c = 0; c < NCH; ++c) {
    // ---- P1: rhs = tr@W^T - st ; q = st@W^T  (consumes trR/stR/subR) ----
    f32x4 rhsF[2], qF[2];
#pragma unroll
    for (int u = 0; u < 2; ++u) {
      f32x4 racc = {0.f, 0.f, 0.f, 0.f}, qacc = {0.f, 0.f, 0.f, 0.f};
#pragma unroll
      for (int k = 0; k < 8; ++k) {
        bf16x8 wb = ldfrag(&WbL[lr][k * 32 + lq * 8]);
        racc = mfma16(asfrag(trR[u][k]), wb, racc);
        qacc = mfma16(asfrag(stR[u][k]), wb, qacc);
      }
#pragma unroll
      for (int r = 0; r < 4; ++r) racc[r] -= bf2f(subR[u][r]);
      rhsF[u] = racc; qF[u] = qacc;
      ushort4 pk;
      pk.x = f2bf(racc.x); pk.y = f2bf(racc.y);
      pk.z = f2bf(racc.z); pk.w = f2bf(racc.w);
      *(ushort4*)(&RpL[w + 8 * u][lr * RP + lq * 4]) = pk;
    }

    // ---- issue this chunk's Lb + trT loads (consumed in P4, cover=P2+P3) --
    uint4 lbRa[4], lbRb[8], trTR[2][8];
    {
      const u16* lb0 = LbG + ((size_t)(c * 16 + w) * 8) * 512 + lr * 32 + lq * 8;
      const u16* lb1 = lb0 + 8ull * 8 * 512;
#pragma unroll
      for (int sp = 0; sp < 4; ++sp)
        if (sp < nL0) lbRa[sp] = *(const uint4*)(lb0 + sp * 512);
#pragma unroll
      for (int sp = 0; sp < 8; ++sp)
        if (sp < nL1) lbRb[sp] = *(const uint4*)(lb1 + sp * 512);
#pragma unroll
      for (int u = 0; u < 2; ++u) {
        const int d2b = w + 8 * u;
#pragma unroll
        for (int sp = 0; sp < 8; ++sp) {
          const int s0 = 2 * sp + (lq >> 1);
          trTR[u][sp] = *(const uint4*)(trT +
              ((size_t)(c * CC + s0) * 256 + d2b * 16 + lr) * 16 + (lq & 1) * 8);
        }
      }
    }

    wg_barrier();  // b1

    // ---- P2: y1 = A @ rhs (strictly-lower blocks only) ----
    f32x4 y1F[2];
    {
      f32x4 acc = {0.f, 0.f, 0.f, 0.f};
#pragma unroll
      for (int sp = 0; sp < 4; ++sp)
        if (sp < nA0) {
          bf16x8 bf = ldfrag(&RpL[2 * sp + (lq >> 1)][lr * RP + (lq & 1) * 8]);
          acc = mfma16(asfrag(agRa[sp]), bf, acc);
        }
      y1F[0] = acc;
      ushort4 pk;
      pk.x = f2bf(acc.x); pk.y = f2bf(acc.y);
      pk.z = f2bf(acc.z); pk.w = f2bf(acc.w);
      *(ushort4*)(&Y1L[w][lr * RP + lq * 4]) = pk;
    }
    {
      f32x4 acc = {0.f, 0.f, 0.f, 0.f};
#pragma unroll
      for (int sp = 0; sp < 8; ++sp)
        if (sp < nA1) {
          bf16x8 bf = ldfrag(&RpL[2 * sp + (lq >> 1)][lr * RP + (lq & 1) * 8]);
          acc = mfma16(asfrag(agRb[sp]), bf, acc);
        }
      y1F[1] = acc;
      ushort4 pk;
      pk.x = f2bf(acc.x); pk.y = f2bf(acc.y);
      pk.z = f2bf(acc.z); pk.w = f2bf(acc.w);
      *(ushort4*)(&Y1L[w + 8][lr * RP + lq * 4]) = pk;
    }

    wg_barrier();  // b2

    // ---- P3: y2 = A @ y1 ; Dp = -k*(rhs - k*y1 + k^2*y2) ----
    {
      f32x4 acc = {0.f, 0.f, 0.f, 0.f};
#pragma unroll
      for (int sp = 0; sp < 4; ++sp)
        if (sp < nA0) {
          bf16x8 bf = ldfrag(&Y1L[2 * sp + (lq >> 1)][lr * RP + (lq & 1) * 8]);
          acc = mfma16(asfrag(agRa[sp]), bf, acc);
        }
      ushort4 pk;
#pragma unroll
      for (int r = 0; r < 4; ++r) {
        float dv = rhsF[0][r] - KAPPA * y1F[0][r] + (KAPPA * KAPPA) * acc[r];
        ((u16*)&pk)[r] = f2bf(-KAPPA * dv);
      }
      *(ushort4*)(&DpL[w][lr * RP + lq * 4]) = pk;
    }
    {
      f32x4 acc = {0.f, 0.f, 0.f, 0.f};
#pragma unroll
      for (int sp = 0; sp < 8; ++sp)
        if (sp < nA1) {
          bf16x8 bf = ldfrag(&Y1L[2 * sp + (lq >> 1)][lr * RP + (lq & 1) * 8]);
          acc = mfma16(asfrag(agRb[sp]), bf, acc);
        }
      ushort4 pk;
#pragma unroll
      for (int r = 0; r < 4; ++r) {
        float dv = rhsF[1][r] - KAPPA * y1F[1][r] + (KAPPA * KAPPA) * acc[r];
        ((u16*)&pk)[r] = f2bf(-KAPPA * dv);
      }
      *(ushort4*)(&DpL[w + 8][lr * RP + lq * 4]) = pk;
    }

    wg_barrier();  // b3

    // ---- prefetch next chunk: tr frags (cover = P4a+P4b+b4) ----
    if (c + 1 < NCH) {
#pragma unroll
      for (int u = 0; u < 2; ++u) {
        const size_t T = (size_t)(c + 1) * CC + w + 8 * u;
        const u16* trt = tr + (T * 16 + lr) * 256 + lq * 8;
#pragma unroll
        for (int k = 0; k < 8; ++k) trR[u][k] = *(const uint4*)(trt + k * 32);
      }
    }

    // ---- P4a: Out = q + Lb @ Dp ; plain store ----
    {
      f32x4 acc = qF[0];
#pragma unroll
      for (int sp = 0; sp < 4; ++sp)
        if (sp < nL0) {
          bf16x8 bf = ldfrag(&DpL[2 * sp + (lq >> 1)][lr * RP + (lq & 1) * 8]);
          acc = mfma16(asfrag(lbRa[sp]), bf, acc);
        }
      const size_t T = (size_t)c * CC + w;
#pragma unroll
      for (int r = 0; r < 4; ++r) {
        size_t oi = ((size_t)(lq * 4 + r) * SS + T) * SD + d1b * 16 + lr;
        out[oi] = acc[r];
      }
    }
    {
      f32x4 acc = qF[1];
#pragma unroll
      for (int sp = 0; sp < 8; ++sp)
        if (sp < nL1) {
          bf16x8 bf = ldfrag(&DpL[2 * sp + (lq >> 1)][lr * RP + (lq & 1) * 8]);
          acc = mfma16(asfrag(lbRb[sp]), bf, acc);
        }
      const size_t T = (size_t)c * CC + w + 8;
#pragma unroll
      for (int r = 0; r < 4; ++r) {
        size_t oi = ((size_t)(lq * 4 + r) * SS + T) * SD + d1b * 16 + lr;
        out[oi] = acc[r];
      }
    }

    // ---- prefetch next chunk: st frags + sub scalars (cover = P4b+b4) ----
    if (c + 1 < NCH) {
#pragma unroll
      for (int u = 0; u < 2; ++u) {
        const size_t T = (size_t)(c + 1) * CC + w + 8 * u;
        const u16* stt = st + (T * 16 + lr) * 256 + lq * 8;
#pragma unroll
        for (int k = 0; k < 8; ++k) stR[u][k] = *(const uint4*)(stt + k * 32);
#pragma unroll
        for (int r = 0; r < 4; ++r)
          subR[u][r] = st[(T * 16 + lq * 4 + r) * 256 + d1b * 16 + lr];
      }
    }

    // ---- P4b: dW = Dp^T-stack @ trT ; apply to WfL and WbL ----
    bf16x8 afR[8];
#pragma unroll
    for (int sp = 0; sp < 8; ++sp)
      afR[sp] = ldfrag(&DpL[2 * sp + (lq >> 1)][lr * RP + (lq & 1) * 8]);
#pragma unroll
    for (int u = 0; u < 2; ++u) {
      const int d2b = w + 8 * u;
      f32x4 acc = {0.f, 0.f, 0.f, 0.f};
#pragma unroll
      for (int sp = 0; sp < 8; ++sp)
        acc = mfma16(afR[sp], asfrag(trTR[u][sp]), acc);
#pragma unroll
      for (int r = 0; r < 4; ++r) {
        float nw = WfL[lq * 4 + r][d2b * 16 + lr] + acc[r];
        WfL[lq * 4 + r][d2b * 16 + lr] = nw;
        WbL[lq * 4 + r][d2b * 16 + lr] = f2bf(nw);
      }
    }

    // ---- prefetch next chunk: AG frags (cover = b4 + next P1) ----
    if (c + 1 < NCH) {
      const u16* ag0 = AG + ((size_t)((c + 1) * 16 + w) * 8) * 512 + lr * 32 + lq * 8;
      const u16* ag1 = ag0 + 8ull * 8 * 512;
#pragma unroll
      for (int sp = 0; sp < 4; ++sp)
        if (sp < nA0) agRa[sp] = *(const uint4*)(ag0 + sp * 512);
#pragma unroll
      for (int sp = 0; sp < 8; ++sp)
        if (sp < nA1) agRb[sp] = *(const uint4*)(ag1 + sp * 512);
    }

    wg_barrier();  // b4: W ready for next chunk
  }
}

extern "C" void kernel_launch(void* const* d_in, const int* in_sizes, int n_in,
                              void* d_out, int out_size, void* d_ws, size_t ws_size,
                              hipStream_t stream) {
  const float* x     = (const float*)d_in[0];
  const float* noise = (const float*)d_in[1];
  const float* a1    = (const float*)d_in[2];
  const float* a2    = (const float*)d_in[3];
  const float* Wttt  = (const float*)d_in[4];
  const float* Wproj = (const float*)d_in[5];
  const float* ffa   = (const float*)d_in[6];
  const float* ffb   = (const float*)d_in[7];
  const float* ffg   = (const float*)d_in[8];
  const float* ffe   = (const float*)d_in[9];
  float* out = (float*)d_out;

  const size_t N = (size_t)SB * SS * SD;   // 8388608 elements
  u16* tr  = (u16*)d_ws;
  u16* st  = tr + N;
  u16* trT = st + N;
  u16* AG  = trT + N;
  u16* LbG = AG + N;    // total ws = 5N*2B ~ 84MB

  prep_kernel<<<8192, 256, 0, stream>>>(x, noise, a1, tr, st, trT);
  gram2_kernel<<<2048, 256, 0, stream>>>(tr, st, AG, LbG);
  scan_kernel<<<16, 512, 0, stream>>>(tr, st, trT, AG, LbG, Wttt, out);
  ff_kernel<<<dim3(512, 4), 256, 0, stream>>>(x, a2, Wproj, ffa, ffb, ffg, ffe, out);
}

// Round 2
// 2726.740 us; speedup vs baseline: 1.3391x; 1.3391x over previous
//
#include <hip/hip_runtime.h>

typedef unsigned short u16;
typedef unsigned int u32;
typedef __attribute__((ext_vector_type(8))) short bf16x8;
typedef __attribute__((ext_vector_type(4))) float f32x4;

#define SB 16
#define SS 2048
#define SD 256
#define CC 16            // chunk length
#define NCH (SS / CC)    // 128 chunks
#define KAPPA 4.8828125e-6f   // 0.01 * 2/(16*256)
#define RP 24            // u16 pitch of transposed 16x16 publish tiles

__device__ __forceinline__ u16 f2bf(float f) {
  u32 u = __float_as_uint(f);
  u = (u + 0x7FFFu + ((u >> 16) & 1u)) >> 16;
  return (u16)u;
}
__device__ __forceinline__ float bf2f(u16 u) { return __uint_as_float((u32)u << 16); }

__device__ __forceinline__ bf16x8 ldfrag(const u16* p) {
  union { uint4 u; bf16x8 f; } cv;
  cv.u = *(const uint4*)p;
  return cv.f;
}
__device__ __forceinline__ bf16x8 asfrag(uint4 q) {
  union { uint4 u; bf16x8 f; } cv;
  cv.u = q;
  return cv.f;
}
__device__ __forceinline__ f32x4 mfma16(bf16x8 a, bf16x8 b, f32x4 c) {
  return __builtin_amdgcn_mfma_f32_16x16x32_bf16(a, b, c, 0, 0, 0);
}

// lgkm-only workgroup barrier (m201-verified pattern): orders LDS publish
// across waves but does NOT drain vmcnt, so prefetched global loads stay
// in flight across the barrier.  sched_barrier(0) pins placement; no
// "memory" clobber on the asm so the compiler's static vmcnt counting of
// surrounding loads survives.
__device__ __forceinline__ void wg_barrier() {
  __builtin_amdgcn_sched_barrier(0);
  asm volatile("s_waitcnt lgkmcnt(0)");
  __builtin_amdgcn_s_barrier();
  __builtin_amdgcn_sched_barrier(0);
}

// Straight-line masked triangular load: always loads (clamped block index,
// duplicate reads are L1 hits), zeroes the fragment branch-free when the
// block is outside the triangle.  Wave-uniform n; no control flow.
__device__ __forceinline__ uint4 ldmask(const u16* p, int sp, int n) {
  const int spc = (sp < n) ? sp : 0;
  uint4 v = *(const uint4*)(p + (size_t)spc * 512);
  const u32 m = (sp < n) ? 0xFFFFFFFFu : 0u;
  v.x &= m; v.y &= m; v.z &= m; v.w &= m;
  return v;
}

// ---------------- prep: train/state (bf16 [t][b][d]) + trainT ([t][d][b]) ----
__global__ __launch_bounds__(256) void prep_kernel(
    const float* __restrict__ x, const float* __restrict__ noise,
    const float* __restrict__ a1,
    u16* __restrict__ train, u16* __restrict__ state, u16* __restrict__ trainT) {
  size_t i4 = (size_t)blockIdx.x * 256 + threadIdx.x;
  size_t base = i4 * 4;
  int d = (int)(base & 255);
  int t = (int)((base >> 8) & 2047);
  int b = (int)(base >> 19);
  float4 xv = *(const float4*)(x + base);
  float4 nv = *(const float4*)(noise + base);
  float4 av = *(const float4*)(a1 + d);
  float m0 = tanhf(av.x * xv.x);
  float m1 = tanhf(av.y * xv.y);
  float m2 = tanhf(av.z * xv.z);
  float m3 = tanhf(av.w * xv.w);
  size_t dst = ((size_t)t * SB + b) * SD + d;
  ushort4 tr, st;
  tr.x = f2bf(m0 + nv.x); tr.y = f2bf(m1 + nv.y);
  tr.z = f2bf(m2 + nv.z); tr.w = f2bf(m3 + nv.w);
  st.x = f2bf(m0); st.y = f2bf(m1); st.z = f2bf(m2); st.w = f2bf(m3);
  *(ushort4*)(train + dst) = tr;
  *(ushort4*)(state + dst) = st;
  size_t tb = ((size_t)t * SD + d) * SB + b;   // trainT[t][d][b]
  trainT[tb + 0 * SB] = tr.x;
  trainT[tb + 1 * SB] = tr.y;
  trainT[tb + 2 * SB] = tr.z;
  trainT[tb + 3 * SB] = tr.w;
}

// ---------------- gram2: AG[c][t][sp][16][32], LbG likewise (zero-filled) ----
__global__ __launch_bounds__(256) void gram2_kernel(
    const u16* __restrict__ tr, const u16* __restrict__ st,
    u16* __restrict__ AG, u16* __restrict__ LbG) {
  const int cb = blockIdx.x;        // c*16 + t
  const int c = cb >> 4, t = cb & 15;
  const int tid = threadIdx.x, lane = tid & 63, wv = tid >> 6;
  const int lr = lane & 15, lq = lane >> 4;
  const size_t Tt = (size_t)cb;
  bf16x8 trF[8], stF[8];
#pragma unroll
  for (int k = 0; k < 8; ++k) {
    trF[k] = ldfrag(tr + (Tt * 16 + lr) * 256 + k * 32 + lq * 8);
    stF[k] = ldfrag(st + (Tt * 16 + lr) * 256 + k * 32 + lq * 8);
  }
  for (int ii = 0; ii < 2; ++ii) {
    const int sp = wv + ii * 4;
    u16* dA = AG + ((size_t)cb * 8 + sp) * 512;
    u16* dL = LbG + ((size_t)cb * 8 + sp) * 512;
#pragma unroll
    for (int h = 0; h < 2; ++h) {
      const int s = 2 * sp + h;
      f32x4 accA = {0.f, 0.f, 0.f, 0.f}, accL = {0.f, 0.f, 0.f, 0.f};
      if (s <= t) {
        const u16* bsrc = tr + ((size_t)(c * 16 + s) * 16 + lr) * 256 + lq * 8;
#pragma unroll
        for (int k = 0; k < 8; ++k) {
          bf16x8 bk = ldfrag(bsrc + k * 32);
          if (s < t) accA = mfma16(trF[k], bk, accA);
          accL = mfma16(stF[k], bk, accL);
        }
      }
#pragma unroll
      for (int r = 0; r < 4; ++r) {
        int idx = (lq * 4 + r) * 32 + h * 16 + lr;
        dA[idx] = (s < t) ? f2bf(accA[r]) : (u16)0;
        dL[idx] = (s <= t) ? f2bf(accL[r]) : (u16)0;
      }
    }
  }
}

// ---------------- ff path: out = u .* (v @ Wp^T) + prev(out)  --------------
__global__ __launch_bounds__(256) void ff_kernel(
    const float* __restrict__ x, const float* __restrict__ a2,
    const float* __restrict__ Wp, const float* __restrict__ ffa,
    const float* __restrict__ ffb, const float* __restrict__ ffg_,
    const float* __restrict__ ffe_, float* __restrict__ out) {
  __shared__ float As[32][68];
  __shared__ float Bs[32][68];
  const int tid = threadIdx.x;
  const int gm0 = blockIdx.x * 64;
  const int gn0 = blockIdx.y * 64;
  const int tm = tid & 15, tn = tid >> 4;
  const int lr = tid & 63;
  const int lq = tid >> 6;
  float acc[4][4];
#pragma unroll
  for (int i = 0; i < 4; i++)
#pragma unroll
    for (int j = 0; j < 4; j++) acc[i][j] = 0.f;

  for (int k0 = 0; k0 < 256; k0 += 32) {
    {
      const float* xp = x + (size_t)(gm0 + lr) * 256 + k0 + lq * 8;
      float4 v0 = *(const float4*)(xp);
      float4 v1 = *(const float4*)(xp + 4);
      const float* ap = a2 + k0 + lq * 8;
      float4 a0 = *(const float4*)(ap);
      float4 a1v = *(const float4*)(ap + 4);
      As[lq * 8 + 0][lr] = tanhf(a0.x * v0.x);
      As[lq * 8 + 1][lr] = tanhf(a0.y * v0.y);
      As[lq * 8 + 2][lr] = tanhf(a0.z * v0.z);
      As[lq * 8 + 3][lr] = tanhf(a0.w * v0.w);
      As[lq * 8 + 4][lr] = tanhf(a1v.x * v1.x);
      As[lq * 8 + 5][lr] = tanhf(a1v.y * v1.y);
      As[lq * 8 + 6][lr] = tanhf(a1v.z * v1.z);
      As[lq * 8 + 7][lr] = tanhf(a1v.w * v1.w);
      const float* wp = Wp + (size_t)(gn0 + lr) * 256 + k0 + lq * 8;
      float4 w0 = *(const float4*)(wp);
      float4 w1 = *(const float4*)(wp + 4);
      Bs[lq * 8 + 0][lr] = w0.x; Bs[lq * 8 + 1][lr] = w0.y;
      Bs[lq * 8 + 2][lr] = w0.z; Bs[lq * 8 + 3][lr] = w0.w;
      Bs[lq * 8 + 4][lr] = w1.x; Bs[lq * 8 + 5][lr] = w1.y;
      Bs[lq * 8 + 6][lr] = w1.z; Bs[lq * 8 + 7][lr] = w1.w;
    }
    __syncthreads();
#pragma unroll
    for (int k = 0; k < 32; ++k) {
      float4 av4 = *(const float4*)&As[k][tm * 4];
      float4 bv4 = *(const float4*)&Bs[k][tn * 4];
      float a[4] = {av4.x, av4.y, av4.z, av4.w};
      float b[4] = {bv4.x, bv4.y, bv4.z, bv4.w};
#pragma unroll
      for (int i = 0; i < 4; i++)
#pragma unroll
        for (int j = 0; j < 4; j++) acc[i][j] += a[i] * b[j];
    }
    __syncthreads();
  }
  const float ga = ffg_[0], et = ffe_[0];
#pragma unroll
  for (int ii = 0; ii < 4; ++ii) {
    int row = gm0 + tm * 4 + ii;
    int col = gn0 + tn * 4;
    float4 xv = *(const float4*)(x + (size_t)row * 256 + col);
    float4 prev = *(const float4*)(out + (size_t)row * 256 + col);
    float4 fa = *(const float4*)(ffa + col);
    float4 fb = *(const float4*)(ffb + col);
    float4 a2v = *(const float4*)(a2 + col);
    float xs[4] = {xv.x, xv.y, xv.z, xv.w};
    float fas[4] = {fa.x, fa.y, fa.z, fa.w};
    float fbs[4] = {fb.x, fb.y, fb.z, fb.w};
    float a2s[4] = {a2v.x, a2v.y, a2v.z, a2v.w};
    float pv[4] = {prev.x, prev.y, prev.z, prev.w};
    float res[4];
#pragma unroll
    for (int j = 0; j < 4; ++j) {
      float v = tanhf(a2s[j] * xs[j]);
      float z = fas[j] * v;
      float gelu = 0.5f * z * (1.0f + erff(z * 0.70710678118654752f));
      float u = ga * gelu + et * sinf(fbs[j] * v);
      res[j] = u * acc[ii][j] + pv[j];
    }
    float4 o; o.x = res[0]; o.y = res[1]; o.z = res[2]; o.w = res[3];
    *(float4*)(out + (size_t)row * 256 + col) = o;
  }
}

// ---------------- scan: 16 WGs x 512 thr; wave w owns t=w and t=w+8 --------
// Straight-line pipelined: all loads unconditional (clamped addresses +
// branch-free fragment masking) so the compiler keeps precise vmcnt counts;
// lgkm-only barriers keep prefetches in flight across phases.
__global__ __launch_bounds__(512, 1) void scan_kernel(
    const u16* __restrict__ tr, const u16* __restrict__ st,
    const u16* __restrict__ trT, const u16* __restrict__ AG,
    const u16* __restrict__ LbG, const float* __restrict__ Wttt,
    float* __restrict__ out) {
  __shared__ u16 RpL[CC][16 * RP];   // bf16(rhs) transposed [d1][b]
  __shared__ u16 Y1L[CC][16 * RP];
  __shared__ u16 DpL[CC][16 * RP];
  __shared__ u16 WbL[16][268];       // bf16 W block [d1][d], pitch 268
  __shared__ float WfL[16][268];     // f32 master

  const int tid = threadIdx.x;
  const int lane = tid & 63;
  const int w = tid >> 6;            // wave 0..7
  const int d1b = blockIdx.x;
  const int lr = lane & 15;
  const int lq = lane >> 4;
  // triangular sp-block counts (each sp covers s in {2sp, 2sp+1})
  const int nA0 = (w + 1) >> 1;        // t=w:   blocks with s<t   (0..4)
  const int nA1 = (w + 9) >> 1;        // t=w+8: blocks with s<t   (4..8)
  const int nL0 = (w >> 1) + 1;        // t=w:   blocks with s<=t  (1..4)
  const int nL1 = ((w + 8) >> 1) + 1;  // t=w+8: blocks with s<=t  (5..8)

  // ---- prologue: issue chunk-0 tr/st/sub before the W fill (overlap) ----
  uint4 trR[2][8], stR[2][8];
  u16 subR[2][4];
#pragma unroll
  for (int u = 0; u < 2; ++u) {
    const size_t T = (size_t)(w + 8 * u);
    const u16* trt = tr + (T * 16 + lr) * 256 + lq * 8;
    const u16* stt = st + (T * 16 + lr) * 256 + lq * 8;
#pragma unroll
    for (int k = 0; k < 8; ++k) {
      trR[u][k] = *(const uint4*)(trt + k * 32);
      stR[u][k] = *(const uint4*)(stt + k * 32);
    }
#pragma unroll
    for (int r = 0; r < 4; ++r)
      subR[u][r] = st[(T * 16 + lq * 4 + r) * 256 + d1b * 16 + lr];
  }

  for (int i = tid; i < 16 * 256; i += 512) {
    int r = i >> 8, d = i & 255;
    float wv_ = Wttt[(size_t)(d1b * 16 + r) * 256 + d];
    WfL[r][d] = wv_;
    WbL[r][d] = f2bf(wv_);
  }
  wg_barrier();  // W ready

  for (int c = 0; c < NCH; ++c) {
    const int cn = (c + 1 < NCH) ? (c + 1) : (NCH - 1);  // uniform, branch-free

    // ---- AG loads (masked triangular, cover = P1) ----
    uint4 agRa[4], agRb[8];
    {
      const u16* ag0 = AG + ((size_t)(c * 16 + w) * 8) * 512 + lr * 32 + lq * 8;
      const u16* ag1 = ag0 + (size_t)8 * 8 * 512;
#pragma unroll
      for (int sp = 0; sp < 4; ++sp) agRa[sp] = ldmask(ag0, sp, nA0);
#pragma unroll
      for (int sp = 0; sp < 4; ++sp) agRb[sp] = *(const uint4*)(ag1 + (size_t)sp * 512);
#pragma unroll
      for (int sp = 4; sp < 8; ++sp) agRb[sp] = ldmask(ag1, sp, nA1);
    }

    // ---- P1: rhs = tr@W^T - st ; q = st@W^T ----
    f32x4 rhsF[2], qF[2];
#pragma unroll
    for (int u = 0; u < 2; ++u) {
      f32x4 racc = {0.f, 0.f, 0.f, 0.f}, qacc = {0.f, 0.f, 0.f, 0.f};
#pragma unroll
      for (int k = 0; k < 8; ++k) {
        bf16x8 wb = ldfrag(&WbL[lr][k * 32 + lq * 8]);
        racc = mfma16(asfrag(trR[u][k]), wb, racc);
        qacc = mfma16(asfrag(stR[u][k]), wb, qacc);
      }
#pragma unroll
      for (int r = 0; r < 4; ++r) racc[r] -= bf2f(subR[u][r]);
      rhsF[u] = racc; qF[u] = qacc;
      ushort4 pk;
      pk.x = f2bf(racc.x); pk.y = f2bf(racc.y);
      pk.z = f2bf(racc.z); pk.w = f2bf(racc.w);
      *(ushort4*)(&RpL[w + 8 * u][lr * RP + lq * 4]) = pk;
    }

    // ---- prefetch next-chunk tr + sub into the just-freed regs ----
#pragma unroll
    for (int u = 0; u < 2; ++u) {
      const size_t T = (size_t)cn * CC + w + 8 * u;
      const u16* trt = tr + (T * 16 + lr) * 256 + lq * 8;
#pragma unroll
      for (int k = 0; k < 8; ++k) trR[u][k] = *(const uint4*)(trt + k * 32);
#pragma unroll
      for (int r = 0; r < 4; ++r)
        subR[u][r] = st[(T * 16 + lq * 4 + r) * 256 + d1b * 16 + lr];
    }

    wg_barrier();  // b1

    // ---- Lb loads (masked triangular, cover = P2+P3) ----
    uint4 lbRa[4], lbRb[8];
    {
      const u16* lb0 = LbG + ((size_t)(c * 16 + w) * 8) * 512 + lr * 32 + lq * 8;
      const u16* lb1 = lb0 + (size_t)8 * 8 * 512;
#pragma unroll
      for (int sp = 0; sp < 4; ++sp) lbRa[sp] = ldmask(lb0, sp, nL0);
#pragma unroll
      for (int sp = 0; sp < 5; ++sp) lbRb[sp] = *(const uint4*)(lb1 + (size_t)sp * 512);
#pragma unroll
      for (int sp = 5; sp < 8; ++sp) lbRb[sp] = ldmask(lb1, sp, nL1);
    }

    // ---- P2: y1 = A @ rhs ----
    f32x4 y1F[2];
    {
      f32x4 acc = {0.f, 0.f, 0.f, 0.f};
#pragma unroll
      for (int sp = 0; sp < 4; ++sp) {
        bf16x8 bf = ldfrag(&RpL[2 * sp + (lq >> 1)][lr * RP + (lq & 1) * 8]);
        acc = mfma16(asfrag(agRa[sp]), bf, acc);
      }
      y1F[0] = acc;
      ushort4 pk;
      pk.x = f2bf(acc.x); pk.y = f2bf(acc.y);
      pk.z = f2bf(acc.z); pk.w = f2bf(acc.w);
      *(ushort4*)(&Y1L[w][lr * RP + lq * 4]) = pk;
    }
    {
      f32x4 acc = {0.f, 0.f, 0.f, 0.f};
#pragma unroll
      for (int sp = 0; sp < 8; ++sp) {
        bf16x8 bf = ldfrag(&RpL[2 * sp + (lq >> 1)][lr * RP + (lq & 1) * 8]);
        acc = mfma16(asfrag(agRb[sp]), bf, acc);
      }
      y1F[1] = acc;
      ushort4 pk;
      pk.x = f2bf(acc.x); pk.y = f2bf(acc.y);
      pk.z = f2bf(acc.z); pk.w = f2bf(acc.w);
      *(ushort4*)(&Y1L[w + 8][lr * RP + lq * 4]) = pk;
    }

    wg_barrier();  // b2

    // ---- P3: y2 = A @ y1 ; Dp = -k*(rhs - k*y1 + k^2*y2) ----
    {
      f32x4 acc = {0.f, 0.f, 0.f, 0.f};
#pragma unroll
      for (int sp = 0; sp < 4; ++sp) {
        bf16x8 bf = ldfrag(&Y1L[2 * sp + (lq >> 1)][lr * RP + (lq & 1) * 8]);
        acc = mfma16(asfrag(agRa[sp]), bf, acc);
      }
      ushort4 pk;
#pragma unroll
      for (int r = 0; r < 4; ++r) {
        float dv = rhsF[0][r] - KAPPA * y1F[0][r] + (KAPPA * KAPPA) * acc[r];
        ((u16*)&pk)[r] = f2bf(-KAPPA * dv);
      }
      *(ushort4*)(&DpL[w][lr * RP + lq * 4]) = pk;
    }
    {
      f32x4 acc = {0.f, 0.f, 0.f, 0.f};
#pragma unroll
      for (int sp = 0; sp < 8; ++sp) {
        bf16x8 bf = ldfrag(&Y1L[2 * sp + (lq >> 1)][lr * RP + (lq & 1) * 8]);
        acc = mfma16(asfrag(agRb[sp]), bf, acc);
      }
      ushort4 pk;
#pragma unroll
      for (int r = 0; r < 4; ++r) {
        float dv = rhsF[1][r] - KAPPA * y1F[1][r] + (KAPPA * KAPPA) * acc[r];
        ((u16*)&pk)[r] = f2bf(-KAPPA * dv);
      }
      *(ushort4*)(&DpL[w + 8][lr * RP + lq * 4]) = pk;
    }

    wg_barrier();  // b3

    // ---- trT loads (cover = P4a) ----
    uint4 trTR[2][8];
#pragma unroll
    for (int u = 0; u < 2; ++u) {
      const int d2b = w + 8 * u;
#pragma unroll
      for (int sp = 0; sp < 8; ++sp) {
        const int s0 = 2 * sp + (lq >> 1);
        trTR[u][sp] = *(const uint4*)(trT +
            ((size_t)(c * CC + s0) * 256 + d2b * 16 + lr) * 16 + (lq & 1) * 8);
      }
    }

    // ---- P4a: Out = q + Lb @ Dp ; plain store ----
    {
      f32x4 acc = qF[0];
#pragma unroll
      for (int sp = 0; sp < 4; ++sp) {
        bf16x8 bf = ldfrag(&DpL[2 * sp + (lq >> 1)][lr * RP + (lq & 1) * 8]);
        acc = mfma16(asfrag(lbRa[sp]), bf, acc);
      }
      const size_t T = (size_t)c * CC + w;
#pragma unroll
      for (int r = 0; r < 4; ++r) {
        size_t oi = ((size_t)(lq * 4 + r) * SS + T) * SD + d1b * 16 + lr;
        out[oi] = acc[r];
      }
    }
    {
      f32x4 acc = qF[1];
#pragma unroll
      for (int sp = 0; sp < 8; ++sp) {
        bf16x8 bf = ldfrag(&DpL[2 * sp + (lq >> 1)][lr * RP + (lq & 1) * 8]);
        acc = mfma16(asfrag(lbRb[sp]), bf, acc);
      }
      const size_t T = (size_t)c * CC + w + 8;
#pragma unroll
      for (int r = 0; r < 4; ++r) {
        size_t oi = ((size_t)(lq * 4 + r) * SS + T) * SD + d1b * 16 + lr;
        out[oi] = acc[r];
      }
    }

    // ---- P4b: dW = Dp^T-stack @ trT ; apply to WfL and WbL ----
    bf16x8 afR[8];
#pragma unroll
    for (int sp = 0; sp < 8; ++sp)
      afR[sp] = ldfrag(&DpL[2 * sp + (lq >> 1)][lr * RP + (lq & 1) * 8]);
    {  // u = 0
      f32x4 acc = {0.f, 0.f, 0.f, 0.f};
#pragma unroll
      for (int sp = 0; sp < 8; ++sp)
        acc = mfma16(afR[sp], asfrag(trTR[0][sp]), acc);
#pragma unroll
      for (int r = 0; r < 4; ++r) {
        float nw = WfL[lq * 4 + r][w * 16 + lr] + acc[r];
        WfL[lq * 4 + r][w * 16 + lr] = nw;
        WbL[lq * 4 + r][w * 16 + lr] = f2bf(nw);
      }
    }
    // ---- prefetch next-chunk st into freed regs (cover = P4b-u1 + b4) ----
#pragma unroll
    for (int u = 0; u < 2; ++u) {
      const size_t T = (size_t)cn * CC + w + 8 * u;
      const u16* stt = st + (T * 16 + lr) * 256 + lq * 8;
#pragma unroll
      for (int k = 0; k < 8; ++k) stR[u][k] = *(const uint4*)(stt + k * 32);
    }
    {  // u = 1
      const int d2b = w + 8;
      f32x4 acc = {0.f, 0.f, 0.f, 0.f};
#pragma unroll
      for (int sp = 0; sp < 8; ++sp)
        acc = mfma16(afR[sp], asfrag(trTR[1][sp]), acc);
#pragma unroll
      for (int r = 0; r < 4; ++r) {
        float nw = WfL[lq * 4 + r][d2b * 16 + lr] + acc[r];
        WfL[lq * 4 + r][d2b * 16 + lr] = nw;
        WbL[lq * 4 + r][d2b * 16 + lr] = f2bf(nw);
      }
    }

    wg_barrier();  // b4: W ready for next chunk
  }
}

extern "C" void kernel_launch(void* const* d_in, const int* in_sizes, int n_in,
                              void* d_out, int out_size, void* d_ws, size_t ws_size,
                              hipStream_t stream) {
  const float* x     = (const float*)d_in[0];
  const float* noise = (const float*)d_in[1];
  const float* a1    = (const float*)d_in[2];
  const float* a2    = (const float*)d_in[3];
  const float* Wttt  = (const float*)d_in[4];
  const float* Wproj = (const float*)d_in[5];
  const float* ffa   = (const float*)d_in[6];
  const float* ffb   = (const float*)d_in[7];
  const float* ffg   = (const float*)d_in[8];
  const float* ffe   = (const float*)d_in[9];
  float* out = (float*)d_out;

  const size_t N = (size_t)SB * SS * SD;   // 8388608 elements
  u16* tr  = (u16*)d_ws;
  u16* st  = tr + N;
  u16* trT = st + N;
  u16* AG  = trT + N;
  u16* LbG = AG + N;    // total ws = 5N*2B ~ 84MB

  prep_kernel<<<8192, 256, 0, stream>>>(x, noise, a1, tr, st, trT);
  gram2_kernel<<<2048, 256, 0, stream>>>(tr, st, AG, LbG);
  scan_kernel<<<16, 512, 0, stream>>>(tr, st, trT, AG, LbG, Wttt, out);
  ff_kernel<<<dim3(512, 4), 256, 0, stream>>>(x, a2, Wproj, ffa, ffb, ffg, ffe, out);
}

// Round 3
// 2509.468 us; speedup vs baseline: 1.4550x; 1.0866x over previous
//
#include <hip/hip_runtime.h>

typedef unsigned short u16;
typedef unsigned int u32;
typedef __attribute__((ext_vector_type(8))) short bf16x8;
typedef __attribute__((ext_vector_type(4))) float f32x4;

#define SB 16
#define SS 2048
#define SD 256
#define CC 16            // chunk length
#define NCH (SS / CC)    // 128 chunks
#define KAPPA 4.8828125e-6f   // 0.01 * 2/(16*256)
#define RP 24            // u16 pitch of transposed 16x16 publish tiles

__device__ __forceinline__ u16 f2bf(float f) {
  u32 u = __float_as_uint(f);
  u = (u + 0x7FFFu + ((u >> 16) & 1u)) >> 16;
  return (u16)u;
}
__device__ __forceinline__ float bf2f(u16 u) { return __uint_as_float((u32)u << 16); }

__device__ __forceinline__ bf16x8 ldfrag(const u16* p) {
  union { uint4 u; bf16x8 f; } cv;
  cv.u = *(const uint4*)p;
  return cv.f;
}
__device__ __forceinline__ bf16x8 asfrag(uint4 q) {
  union { uint4 u; bf16x8 f; } cv;
  cv.u = q;
  return cv.f;
}
__device__ __forceinline__ f32x4 mfma16(bf16x8 a, bf16x8 b, f32x4 c) {
  return __builtin_amdgcn_mfma_f32_16x16x32_bf16(a, b, c, 0, 0, 0);
}

// Straight-line masked triangular load: always loads (clamped block index,
// duplicate reads are L1 hits), zeroes the fragment branch-free when the
// block is outside the triangle.  Wave-uniform n; no control flow.
__device__ __forceinline__ uint4 ldmask(const u16* p, int sp, int n) {
  const int spc = (sp < n) ? sp : 0;
  uint4 v = *(const uint4*)(p + (size_t)spc * 512);
  const u32 m = (sp < n) ? 0xFFFFFFFFu : 0u;
  v.x &= m; v.y &= m; v.z &= m; v.w &= m;
  return v;
}

// ---------------- prep: train/state (bf16 [t][b][d]) + trainT ([t][d][b]) ----
__global__ __launch_bounds__(256) void prep_kernel(
    const float* __restrict__ x, const float* __restrict__ noise,
    const float* __restrict__ a1,
    u16* __restrict__ train, u16* __restrict__ state, u16* __restrict__ trainT) {
  size_t i4 = (size_t)blockIdx.x * 256 + threadIdx.x;
  size_t base = i4 * 4;
  int d = (int)(base & 255);
  int t = (int)((base >> 8) & 2047);
  int b = (int)(base >> 19);
  float4 xv = *(const float4*)(x + base);
  float4 nv = *(const float4*)(noise + base);
  float4 av = *(const float4*)(a1 + d);
  float m0 = tanhf(av.x * xv.x);
  float m1 = tanhf(av.y * xv.y);
  float m2 = tanhf(av.z * xv.z);
  float m3 = tanhf(av.w * xv.w);
  size_t dst = ((size_t)t * SB + b) * SD + d;
  ushort4 tr, st;
  tr.x = f2bf(m0 + nv.x); tr.y = f2bf(m1 + nv.y);
  tr.z = f2bf(m2 + nv.z); tr.w = f2bf(m3 + nv.w);
  st.x = f2bf(m0); st.y = f2bf(m1); st.z = f2bf(m2); st.w = f2bf(m3);
  *(ushort4*)(train + dst) = tr;
  *(ushort4*)(state + dst) = st;
  size_t tb = ((size_t)t * SD + d) * SB + b;   // trainT[t][d][b]
  trainT[tb + 0 * SB] = tr.x;
  trainT[tb + 1 * SB] = tr.y;
  trainT[tb + 2 * SB] = tr.z;
  trainT[tb + 3 * SB] = tr.w;
}

// ---------------- gram2: AG[c][t][sp][16][32], LbG likewise (zero-filled) ----
__global__ __launch_bounds__(256) void gram2_kernel(
    const u16* __restrict__ tr, const u16* __restrict__ st,
    u16* __restrict__ AG, u16* __restrict__ LbG) {
  const int cb = blockIdx.x;        // c*16 + t
  const int c = cb >> 4, t = cb & 15;
  const int tid = threadIdx.x, lane = tid & 63, wv = tid >> 6;
  const int lr = lane & 15, lq = lane >> 4;
  const size_t Tt = (size_t)cb;
  bf16x8 trF[8], stF[8];
#pragma unroll
  for (int k = 0; k < 8; ++k) {
    trF[k] = ldfrag(tr + (Tt * 16 + lr) * 256 + k * 32 + lq * 8);
    stF[k] = ldfrag(st + (Tt * 16 + lr) * 256 + k * 32 + lq * 8);
  }
  for (int ii = 0; ii < 2; ++ii) {
    const int sp = wv + ii * 4;
    u16* dA = AG + ((size_t)cb * 8 + sp) * 512;
    u16* dL = LbG + ((size_t)cb * 8 + sp) * 512;
#pragma unroll
    for (int h = 0; h < 2; ++h) {
      const int s = 2 * sp + h;
      f32x4 accA = {0.f, 0.f, 0.f, 0.f}, accL = {0.f, 0.f, 0.f, 0.f};
      if (s <= t) {
        const u16* bsrc = tr + ((size_t)(c * 16 + s) * 16 + lr) * 256 + lq * 8;
#pragma unroll
        for (int k = 0; k < 8; ++k) {
          bf16x8 bk = ldfrag(bsrc + k * 32);
          if (s < t) accA = mfma16(trF[k], bk, accA);
          accL = mfma16(stF[k], bk, accL);
        }
      }
#pragma unroll
      for (int r = 0; r < 4; ++r) {
        int idx = (lq * 4 + r) * 32 + h * 16 + lr;
        dA[idx] = (s < t) ? f2bf(accA[r]) : (u16)0;
        dL[idx] = (s <= t) ? f2bf(accL[r]) : (u16)0;
      }
    }
  }
}

// ---------------- ff path: out = u .* (v @ Wp^T) + prev(out)  --------------
__global__ __launch_bounds__(256) void ff_kernel(
    const float* __restrict__ x, const float* __restrict__ a2,
    const float* __restrict__ Wp, const float* __restrict__ ffa,
    const float* __restrict__ ffb, const float* __restrict__ ffg_,
    const float* __restrict__ ffe_, float* __restrict__ out) {
  __shared__ float As[32][68];
  __shared__ float Bs[32][68];
  const int tid = threadIdx.x;
  const int gm0 = blockIdx.x * 64;
  const int gn0 = blockIdx.y * 64;
  const int tm = tid & 15, tn = tid >> 4;
  const int lr = tid & 63;
  const int lq = tid >> 6;
  float acc[4][4];
#pragma unroll
  for (int i = 0; i < 4; i++)
#pragma unroll
    for (int j = 0; j < 4; j++) acc[i][j] = 0.f;

  for (int k0 = 0; k0 < 256; k0 += 32) {
    {
      const float* xp = x + (size_t)(gm0 + lr) * 256 + k0 + lq * 8;
      float4 v0 = *(const float4*)(xp);
      float4 v1 = *(const float4*)(xp + 4);
      const float* ap = a2 + k0 + lq * 8;
      float4 a0 = *(const float4*)(ap);
      float4 a1v = *(const float4*)(ap + 4);
      As[lq * 8 + 0][lr] = tanhf(a0.x * v0.x);
      As[lq * 8 + 1][lr] = tanhf(a0.y * v0.y);
      As[lq * 8 + 2][lr] = tanhf(a0.z * v0.z);
      As[lq * 8 + 3][lr] = tanhf(a0.w * v0.w);
      As[lq * 8 + 4][lr] = tanhf(a1v.x * v1.x);
      As[lq * 8 + 5][lr] = tanhf(a1v.y * v1.y);
      As[lq * 8 + 6][lr] = tanhf(a1v.z * v1.z);
      As[lq * 8 + 7][lr] = tanhf(a1v.w * v1.w);
      const float* wp = Wp + (size_t)(gn0 + lr) * 256 + k0 + lq * 8;
      float4 w0 = *(const float4*)(wp);
      float4 w1 = *(const float4*)(wp + 4);
      Bs[lq * 8 + 0][lr] = w0.x; Bs[lq * 8 + 1][lr] = w0.y;
      Bs[lq * 8 + 2][lr] = w0.z; Bs[lq * 8 + 3][lr] = w0.w;
      Bs[lq * 8 + 4][lr] = w1.x; Bs[lq * 8 + 5][lr] = w1.y;
      Bs[lq * 8 + 6][lr] = w1.z; Bs[lq * 8 + 7][lr] = w1.w;
    }
    __syncthreads();
#pragma unroll
    for (int k = 0; k < 32; ++k) {
      float4 av4 = *(const float4*)&As[k][tm * 4];
      float4 bv4 = *(const float4*)&Bs[k][tn * 4];
      float a[4] = {av4.x, av4.y, av4.z, av4.w};
      float b[4] = {bv4.x, bv4.y, bv4.z, bv4.w};
#pragma unroll
      for (int i = 0; i < 4; i++)
#pragma unroll
        for (int j = 0; j < 4; j++) acc[i][j] += a[i] * b[j];
    }
    __syncthreads();
  }
  const float ga = ffg_[0], et = ffe_[0];
#pragma unroll
  for (int ii = 0; ii < 4; ++ii) {
    int row = gm0 + tm * 4 + ii;
    int col = gn0 + tn * 4;
    float4 xv = *(const float4*)(x + (size_t)row * 256 + col);
    float4 prev = *(const float4*)(out + (size_t)row * 256 + col);
    float4 fa = *(const float4*)(ffa + col);
    float4 fb = *(const float4*)(ffb + col);
    float4 a2v = *(const float4*)(a2 + col);
    float xs[4] = {xv.x, xv.y, xv.z, xv.w};
    float fas[4] = {fa.x, fa.y, fa.z, fa.w};
    float fbs[4] = {fb.x, fb.y, fb.z, fb.w};
    float a2s[4] = {a2v.x, a2v.y, a2v.z, a2v.w};
    float pv[4] = {prev.x, prev.y, prev.z, prev.w};
    float res[4];
#pragma unroll
    for (int j = 0; j < 4; ++j) {
      float v = tanhf(a2s[j] * xs[j]);
      float z = fas[j] * v;
      float gelu = 0.5f * z * (1.0f + erff(z * 0.70710678118654752f));
      float u = ga * gelu + et * sinf(fbs[j] * v);
      res[j] = u * acc[ii][j] + pv[j];
    }
    float4 o; o.x = res[0]; o.y = res[1]; o.z = res[2]; o.w = res[3];
    *(float4*)(out + (size_t)row * 256 + col) = o;
  }
}

// ---------------- scan: 16 WGs x 1024 thr; wave w owns timestep t=w --------
// R0 structure (phase-local loads, plain __syncthreads) but 16 waves/WG
// (4 waves/SIMD) for 2x the memory-level parallelism per load phase and
// half the per-wave serial MFMA chain.  Triangular AG/LbG loads are
// branch-free masked (stored-zero blocks skipped).
__global__ __launch_bounds__(1024, 1) void scan_kernel(
    const u16* __restrict__ tr, const u16* __restrict__ st,
    const u16* __restrict__ trT, const u16* __restrict__ AG,
    const u16* __restrict__ LbG, const float* __restrict__ Wttt,
    float* __restrict__ out) {
  __shared__ u16 RpL[CC][16 * RP];   // bf16(rhs) transposed [d1][b]
  __shared__ u16 Y1L[CC][16 * RP];
  __shared__ u16 DpL[CC][16 * RP];
  __shared__ u16 WbL[16][268];       // bf16 W block [d1][d], pitch 268
  __shared__ float WfL[16][268];     // f32 master

  const int tid = threadIdx.x;
  const int lane = tid & 63;
  const int w = tid >> 6;            // wave 0..15  == timestep t == d2 block
  const int d1b = blockIdx.x;
  const int lr = lane & 15;
  const int lq = lane >> 4;
  // triangular sp-block counts for t=w (each sp covers s in {2sp, 2sp+1})
  const int nA = (w + 1) >> 1;       // blocks with s<t   (0..8)
  const int nL = (w >> 1) + 1;       // blocks with s<=t  (1..8)

  for (int i = tid; i < 16 * 256; i += 1024) {
    int r = i >> 8, d = i & 255;
    float wv_ = Wttt[(size_t)(d1b * 16 + r) * 256 + d];
    WfL[r][d] = wv_;
    WbL[r][d] = f2bf(wv_);
  }
  __syncthreads();

  for (int c = 0; c < NCH; ++c) {
    const size_t T = (size_t)c * CC + w;

    // ---- P1 loads: tr/st frags + st scalars for t=w ----
    uint4 trR[8], stR[8];
    u16 subR[4];
    {
      const u16* trt = tr + (T * 16 + lr) * 256 + lq * 8;
      const u16* stt = st + (T * 16 + lr) * 256 + lq * 8;
#pragma unroll
      for (int k = 0; k < 8; ++k) {
        trR[k] = *(const uint4*)(trt + k * 32);
        stR[k] = *(const uint4*)(stt + k * 32);
      }
#pragma unroll
      for (int r = 0; r < 4; ++r)
        subR[r] = st[(T * 16 + lq * 4 + r) * 256 + d1b * 16 + lr];
    }

    // ---- P1 compute: rhs = tr@W^T - st ; q = st@W^T ----
    f32x4 rhsF, qF;
    {
      f32x4 racc = {0.f, 0.f, 0.f, 0.f}, qacc = {0.f, 0.f, 0.f, 0.f};
#pragma unroll
      for (int k = 0; k < 8; ++k) {
        bf16x8 wb = ldfrag(&WbL[lr][k * 32 + lq * 8]);
        racc = mfma16(asfrag(trR[k]), wb, racc);
        qacc = mfma16(asfrag(stR[k]), wb, qacc);
      }
#pragma unroll
      for (int r = 0; r < 4; ++r) racc[r] -= bf2f(subR[r]);
      rhsF = racc; qF = qacc;
      ushort4 pk;
      pk.x = f2bf(racc.x); pk.y = f2bf(racc.y);
      pk.z = f2bf(racc.z); pk.w = f2bf(racc.w);
      *(ushort4*)(&RpL[w][lr * RP + lq * 4]) = pk;
    }

    // ---- AG loads (masked triangular; cover = b1 drain) ----
    uint4 agR[8];
    {
      const u16* ag0 = AG + ((size_t)(c * 16 + w) * 8) * 512 + lr * 32 + lq * 8;
#pragma unroll
      for (int sp = 0; sp < 8; ++sp) agR[sp] = ldmask(ag0, sp, nA);
    }

    __syncthreads();  // b1

    // ---- P2: y1 = A @ rhs ----
    f32x4 y1F;
    {
      f32x4 acc = {0.f, 0.f, 0.f, 0.f};
#pragma unroll
      for (int sp = 0; sp < 8; ++sp) {
        bf16x8 bf = ldfrag(&RpL[2 * sp + (lq >> 1)][lr * RP + (lq & 1) * 8]);
        acc = mfma16(asfrag(agR[sp]), bf, acc);
      }
      y1F = acc;
      ushort4 pk;
      pk.x = f2bf(acc.x); pk.y = f2bf(acc.y);
      pk.z = f2bf(acc.z); pk.w = f2bf(acc.w);
      *(ushort4*)(&Y1L[w][lr * RP + lq * 4]) = pk;
    }

    // ---- Lb loads (masked triangular; cover = b2 + P3) ----
    uint4 lbR[8];
    {
      const u16* lb0 = LbG + ((size_t)(c * 16 + w) * 8) * 512 + lr * 32 + lq * 8;
#pragma unroll
      for (int sp = 0; sp < 8; ++sp) lbR[sp] = ldmask(lb0, sp, nL);
    }

    __syncthreads();  // b2

    // ---- P3: y2 = A @ y1 ; Dp = -k*(rhs - k*y1 + k^2*y2) ----
    {
      f32x4 acc = {0.f, 0.f, 0.f, 0.f};
#pragma unroll
      for (int sp = 0; sp < 8; ++sp) {
        bf16x8 bf = ldfrag(&Y1L[2 * sp + (lq >> 1)][lr * RP + (lq & 1) * 8]);
        acc = mfma16(asfrag(agR[sp]), bf, acc);
      }
      ushort4 pk;
#pragma unroll
      for (int r = 0; r < 4; ++r) {
        float dv = rhsF[r] - KAPPA * y1F[r] + (KAPPA * KAPPA) * acc[r];
        ((u16*)&pk)[r] = f2bf(-KAPPA * dv);
      }
      *(ushort4*)(&DpL[w][lr * RP + lq * 4]) = pk;
    }

    __syncthreads();  // b3

    // ---- trT loads for d2b=w (cover = P4a) ----
    uint4 trTR[8];
#pragma unroll
    for (int sp = 0; sp < 8; ++sp) {
      const int s0 = 2 * sp + (lq >> 1);
      trTR[sp] = *(const uint4*)(trT +
          ((size_t)(c * CC + s0) * 256 + w * 16 + lr) * 16 + (lq & 1) * 8);
    }

    // ---- P4a: Out = q + Lb @ Dp ; plain store ----
    {
      f32x4 acc = qF;
#pragma unroll
      for (int sp = 0; sp < 8; ++sp) {
        bf16x8 bf = ldfrag(&DpL[2 * sp + (lq >> 1)][lr * RP + (lq & 1) * 8]);
        acc = mfma16(asfrag(lbR[sp]), bf, acc);
      }
#pragma unroll
      for (int r = 0; r < 4; ++r) {
        size_t oi = ((size_t)(lq * 4 + r) * SS + T) * SD + d1b * 16 + lr;
        out[oi] = acc[r];
      }
    }

    // ---- P4b: dW(:, d2 block w) = Dp^T-stack @ trT ; apply to WfL/WbL ----
    {
      f32x4 acc = {0.f, 0.f, 0.f, 0.f};
#pragma unroll
      for (int sp = 0; sp < 8; ++sp) {
        bf16x8 af = ldfrag(&DpL[2 * sp + (lq >> 1)][lr * RP + (lq & 1) * 8]);
        acc = mfma16(af, asfrag(trTR[sp]), acc);
      }
#pragma unroll
      for (int r = 0; r < 4; ++r) {
        float nw = WfL[lq * 4 + r][w * 16 + lr] + acc[r];
        WfL[lq * 4 + r][w * 16 + lr] = nw;
        WbL[lq * 4 + r][w * 16 + lr] = f2bf(nw);
      }
    }

    __syncthreads();  // b4: W ready for next chunk
  }
}

extern "C" void kernel_launch(void* const* d_in, const int* in_sizes, int n_in,
                              void* d_out, int out_size, void* d_ws, size_t ws_size,
                              hipStream_t stream) {
  const float* x     = (const float*)d_in[0];
  const float* noise = (const float*)d_in[1];
  const float* a1    = (const float*)d_in[2];
  const float* a2    = (const float*)d_in[3];
  const float* Wttt  = (const float*)d_in[4];
  const float* Wproj = (const float*)d_in[5];
  const float* ffa   = (const float*)d_in[6];
  const float* ffb   = (const float*)d_in[7];
  const float* ffg   = (const float*)d_in[8];
  const float* ffe   = (const float*)d_in[9];
  float* out = (float*)d_out;

  const size_t N = (size_t)SB * SS * SD;   // 8388608 elements
  u16* tr  = (u16*)d_ws;
  u16* st  = tr + N;
  u16* trT = st + N;
  u16* AG  = trT + N;
  u16* LbG = AG + N;    // total ws = 5N*2B ~ 84MB

  prep_kernel<<<8192, 256, 0, stream>>>(x, noise, a1, tr, st, trT);
  gram2_kernel<<<2048, 256, 0, stream>>>(tr, st, AG, LbG);
  scan_kernel<<<16, 1024, 0, stream>>>(tr, st, trT, AG, LbG, Wttt, out);
  ff_kernel<<<dim3(512, 4), 256, 0, stream>>>(x, a2, Wproj, ffa, ffb, ffg, ffe, out);
}

// Round 4
// 2032.389 us; speedup vs baseline: 1.7965x; 1.2347x over previous
//
#include <hip/hip_runtime.h>

typedef unsigned short u16;
typedef unsigned int u32;
typedef __attribute__((ext_vector_type(8))) short bf16x8;
typedef __attribute__((ext_vector_type(4))) float f32x4;

#define SB 16
#define SS 2048
#define SD 256
#define CC 16            // chunk length
#define NCH (SS / CC)    // 128 chunks
#define KAPPA 4.8828125e-6f   // 0.01 * 2/(16*256)
#define RP 24            // u16 pitch of transposed 16x16 publish tiles

__device__ __forceinline__ u16 f2bf(float f) {
  u32 u = __float_as_uint(f);
  u = (u + 0x7FFFu + ((u >> 16) & 1u)) >> 16;
  return (u16)u;
}
__device__ __forceinline__ float bf2f(u16 u) { return __uint_as_float((u32)u << 16); }

__device__ __forceinline__ bf16x8 ldfrag(const u16* p) {
  union { uint4 u; bf16x8 f; } cv;
  cv.u = *(const uint4*)p;
  return cv.f;
}
__device__ __forceinline__ bf16x8 asfrag(uint4 q) {
  union { uint4 u; bf16x8 f; } cv;
  cv.u = q;
  return cv.f;
}
__device__ __forceinline__ f32x4 mfma16(bf16x8 a, bf16x8 b, f32x4 c) {
  return __builtin_amdgcn_mfma_f32_16x16x32_bf16(a, b, c, 0, 0, 0);
}

// Straight-line masked triangular load: always loads (clamped block index,
// duplicate reads are L1 hits), zeroes the fragment branch-free when the
// block is outside the triangle.  Wave-uniform n; no control flow.
__device__ __forceinline__ uint4 ldmask(const u16* p, int sp, int n) {
  const int spc = (sp < n) ? sp : 0;
  uint4 v = *(const uint4*)(p + (size_t)spc * 512);
  const u32 m = (sp < n) ? 0xFFFFFFFFu : 0u;
  v.x &= m; v.y &= m; v.z &= m; v.w &= m;
  return v;
}

// ---------------- prep: train/state (bf16 [t][b][d]) + trainT ([t][d][b]) ----
__global__ __launch_bounds__(256) void prep_kernel(
    const float* __restrict__ x, const float* __restrict__ noise,
    const float* __restrict__ a1,
    u16* __restrict__ train, u16* __restrict__ state, u16* __restrict__ trainT) {
  size_t i4 = (size_t)blockIdx.x * 256 + threadIdx.x;
  size_t base = i4 * 4;
  int d = (int)(base & 255);
  int t = (int)((base >> 8) & 2047);
  int b = (int)(base >> 19);
  float4 xv = *(const float4*)(x + base);
  float4 nv = *(const float4*)(noise + base);
  float4 av = *(const float4*)(a1 + d);
  float m0 = tanhf(av.x * xv.x);
  float m1 = tanhf(av.y * xv.y);
  float m2 = tanhf(av.z * xv.z);
  float m3 = tanhf(av.w * xv.w);
  size_t dst = ((size_t)t * SB + b) * SD + d;
  ushort4 tr, st;
  tr.x = f2bf(m0 + nv.x); tr.y = f2bf(m1 + nv.y);
  tr.z = f2bf(m2 + nv.z); tr.w = f2bf(m3 + nv.w);
  st.x = f2bf(m0); st.y = f2bf(m1); st.z = f2bf(m2); st.w = f2bf(m3);
  *(ushort4*)(train + dst) = tr;
  *(ushort4*)(state + dst) = st;
  size_t tb = ((size_t)t * SD + d) * SB + b;   // trainT[t][d][b]
  trainT[tb + 0 * SB] = tr.x;
  trainT[tb + 1 * SB] = tr.y;
  trainT[tb + 2 * SB] = tr.z;
  trainT[tb + 3 * SB] = tr.w;
}

// ---------------- gram2: AG[c][t][sp][16][32], LbG likewise (zero-filled) ----
__global__ __launch_bounds__(256) void gram2_kernel(
    const u16* __restrict__ tr, const u16* __restrict__ st,
    u16* __restrict__ AG, u16* __restrict__ LbG) {
  const int cb = blockIdx.x;        // c*16 + t
  const int c = cb >> 4, t = cb & 15;
  const int tid = threadIdx.x, lane = tid & 63, wv = tid >> 6;
  const int lr = lane & 15, lq = lane >> 4;
  const size_t Tt = (size_t)cb;
  bf16x8 trF[8], stF[8];
#pragma unroll
  for (int k = 0; k < 8; ++k) {
    trF[k] = ldfrag(tr + (Tt * 16 + lr) * 256 + k * 32 + lq * 8);
    stF[k] = ldfrag(st + (Tt * 16 + lr) * 256 + k * 32 + lq * 8);
  }
  for (int ii = 0; ii < 2; ++ii) {
    const int sp = wv + ii * 4;
    u16* dA = AG + ((size_t)cb * 8 + sp) * 512;
    u16* dL = LbG + ((size_t)cb * 8 + sp) * 512;
#pragma unroll
    for (int h = 0; h < 2; ++h) {
      const int s = 2 * sp + h;
      f32x4 accA = {0.f, 0.f, 0.f, 0.f}, accL = {0.f, 0.f, 0.f, 0.f};
      if (s <= t) {
        const u16* bsrc = tr + ((size_t)(c * 16 + s) * 16 + lr) * 256 + lq * 8;
#pragma unroll
        for (int k = 0; k < 8; ++k) {
          bf16x8 bk = ldfrag(bsrc + k * 32);
          if (s < t) accA = mfma16(trF[k], bk, accA);
          accL = mfma16(stF[k], bk, accL);
        }
      }
#pragma unroll
      for (int r = 0; r < 4; ++r) {
        int idx = (lq * 4 + r) * 32 + h * 16 + lr;
        dA[idx] = (s < t) ? f2bf(accA[r]) : (u16)0;
        dL[idx] = (s <= t) ? f2bf(accL[r]) : (u16)0;
      }
    }
  }
}

// ---------------- ff path: out = u .* (v @ Wp^T) + prev(out)  --------------
__global__ __launch_bounds__(256) void ff_kernel(
    const float* __restrict__ x, const float* __restrict__ a2,
    const float* __restrict__ Wp, const float* __restrict__ ffa,
    const float* __restrict__ ffb, const float* __restrict__ ffg_,
    const float* __restrict__ ffe_, float* __restrict__ out) {
  __shared__ float As[32][68];
  __shared__ float Bs[32][68];
  const int tid = threadIdx.x;
  const int gm0 = blockIdx.x * 64;
  const int gn0 = blockIdx.y * 64;
  const int tm = tid & 15, tn = tid >> 4;
  const int lr = tid & 63;
  const int lq = tid >> 6;
  float acc[4][4];
#pragma unroll
  for (int i = 0; i < 4; i++)
#pragma unroll
    for (int j = 0; j < 4; j++) acc[i][j] = 0.f;

  for (int k0 = 0; k0 < 256; k0 += 32) {
    {
      const float* xp = x + (size_t)(gm0 + lr) * 256 + k0 + lq * 8;
      float4 v0 = *(const float4*)(xp);
      float4 v1 = *(const float4*)(xp + 4);
      const float* ap = a2 + k0 + lq * 8;
      float4 a0 = *(const float4*)(ap);
      float4 a1v = *(const float4*)(ap + 4);
      As[lq * 8 + 0][lr] = tanhf(a0.x * v0.x);
      As[lq * 8 + 1][lr] = tanhf(a0.y * v0.y);
      As[lq * 8 + 2][lr] = tanhf(a0.z * v0.z);
      As[lq * 8 + 3][lr] = tanhf(a0.w * v0.w);
      As[lq * 8 + 4][lr] = tanhf(a1v.x * v1.x);
      As[lq * 8 + 5][lr] = tanhf(a1v.y * v1.y);
      As[lq * 8 + 6][lr] = tanhf(a1v.z * v1.z);
      As[lq * 8 + 7][lr] = tanhf(a1v.w * v1.w);
      const float* wp = Wp + (size_t)(gn0 + lr) * 256 + k0 + lq * 8;
      float4 w0 = *(const float4*)(wp);
      float4 w1 = *(const float4*)(wp + 4);
      Bs[lq * 8 + 0][lr] = w0.x; Bs[lq * 8 + 1][lr] = w0.y;
      Bs[lq * 8 + 2][lr] = w0.z; Bs[lq * 8 + 3][lr] = w0.w;
      Bs[lq * 8 + 4][lr] = w1.x; Bs[lq * 8 + 5][lr] = w1.y;
      Bs[lq * 8 + 6][lr] = w1.z; Bs[lq * 8 + 7][lr] = w1.w;
    }
    __syncthreads();
#pragma unroll
    for (int k = 0; k < 32; ++k) {
      float4 av4 = *(const float4*)&As[k][tm * 4];
      float4 bv4 = *(const float4*)&Bs[k][tn * 4];
      float a[4] = {av4.x, av4.y, av4.z, av4.w};
      float b[4] = {bv4.x, bv4.y, bv4.z, bv4.w};
#pragma unroll
      for (int i = 0; i < 4; i++)
#pragma unroll
        for (int j = 0; j < 4; j++) acc[i][j] += a[i] * b[j];
    }
    __syncthreads();
  }
  const float ga = ffg_[0], et = ffe_[0];
#pragma unroll
  for (int ii = 0; ii < 4; ++ii) {
    int row = gm0 + tm * 4 + ii;
    int col = gn0 + tn * 4;
    float4 xv = *(const float4*)(x + (size_t)row * 256 + col);
    float4 prev = *(const float4*)(out + (size_t)row * 256 + col);
    float4 fa = *(const float4*)(ffa + col);
    float4 fb = *(const float4*)(ffb + col);
    float4 a2v = *(const float4*)(a2 + col);
    float xs[4] = {xv.x, xv.y, xv.z, xv.w};
    float fas[4] = {fa.x, fa.y, fa.z, fa.w};
    float fbs[4] = {fb.x, fb.y, fb.z, fb.w};
    float a2s[4] = {a2v.x, a2v.y, a2v.z, a2v.w};
    float pv[4] = {prev.x, prev.y, prev.z, prev.w};
    float res[4];
#pragma unroll
    for (int j = 0; j < 4; ++j) {
      float v = tanhf(a2s[j] * xs[j]);
      float z = fas[j] * v;
      float gelu = 0.5f * z * (1.0f + erff(z * 0.70710678118654752f));
      float u = ga * gelu + et * sinf(fbs[j] * v);
      res[j] = u * acc[ii][j] + pv[j];
    }
    float4 o; o.x = res[0]; o.y = res[1]; o.z = res[2]; o.w = res[3];
    *(float4*)(out + (size_t)row * 256 + col) = o;
  }
}

// ---------------- scan: 16 WGs x 512 thr; wave w owns t=w and t=w+8 --------
// Exact R0 structure (phase-local loads, plain __syncthreads, no
// cross-chunk register liveness) + static triangular shrink: u=0 arrays
// are 4 blocks (upper half is compile-time zero), boundary blocks masked
// branch-free.  Saves ~10% of per-CU bytes and 18% of MFMAs per chunk.
__global__ __launch_bounds__(512, 1) void scan_kernel(
    const u16* __restrict__ tr, const u16* __restrict__ st,
    const u16* __restrict__ trT, const u16* __restrict__ AG,
    const u16* __restrict__ LbG, const float* __restrict__ Wttt,
    float* __restrict__ out) {
  __shared__ u16 RpL[CC][16 * RP];   // bf16(rhs) transposed [d1][b]
  __shared__ u16 Y1L[CC][16 * RP];
  __shared__ u16 DpL[CC][16 * RP];
  __shared__ u16 WbL[16][268];       // bf16 W block [d1][d], pitch 268
  __shared__ float WfL[16][268];     // f32 master

  const int tid = threadIdx.x;
  const int lane = tid & 63;
  const int w = tid >> 6;            // wave 0..7
  const int d1b = blockIdx.x;
  const int lr = lane & 15;
  const int lq = lane >> 4;
  // triangular sp-block counts (each sp covers s in {2sp, 2sp+1})
  const int nA0 = (w + 1) >> 1;        // t=w:   blocks with s<t   (0..4)
  const int nA1 = (w + 9) >> 1;        // t=w+8: blocks with s<t   (4..8)
  const int nL0 = (w >> 1) + 1;        // t=w:   blocks with s<=t  (1..4)
  const int nL1 = ((w + 8) >> 1) + 1;  // t=w+8: blocks with s<=t  (5..8)

  for (int i = tid; i < 16 * 256; i += 512) {
    int r = i >> 8, d = i & 255;
    float wv_ = Wttt[(size_t)(d1b * 16 + r) * 256 + d];
    WfL[r][d] = wv_;
    WbL[r][d] = f2bf(wv_);
  }
  __syncthreads();

  for (int c = 0; c < NCH; ++c) {
    // ---- prefetch AG frags for both t's (used in P2 AND P3) ----
    uint4 agRa[4], agRb[8];
    {
      const u16* ag0 = AG + ((size_t)(c * 16 + w) * 8) * 512 + lr * 32 + lq * 8;
      const u16* ag1 = ag0 + (size_t)8 * 8 * 512;
#pragma unroll
      for (int sp = 0; sp < 4; ++sp) agRa[sp] = ldmask(ag0, sp, nA0);
#pragma unroll
      for (int sp = 0; sp < 4; ++sp) agRb[sp] = *(const uint4*)(ag1 + (size_t)sp * 512);
#pragma unroll
      for (int sp = 4; sp < 8; ++sp) agRb[sp] = ldmask(ag1, sp, nA1);
    }
    // ---- P1 loads: tr/st frags + st scalars for both t's ----
    uint4 trR[2][8], stR[2][8];
    float sub[2][4];
#pragma unroll
    for (int u = 0; u < 2; ++u) {
      const size_t T = (size_t)c * CC + w + 8 * u;
      const u16* trt = tr + (T * 16 + lr) * 256 + lq * 8;
      const u16* stt = st + (T * 16 + lr) * 256 + lq * 8;
#pragma unroll
      for (int k = 0; k < 8; ++k) {
        trR[u][k] = *(const uint4*)(trt + k * 32);
        stR[u][k] = *(const uint4*)(stt + k * 32);
      }
#pragma unroll
      for (int r = 0; r < 4; ++r)
        sub[u][r] = bf2f(st[(T * 16 + lq * 4 + r) * 256 + d1b * 16 + lr]);
    }

    // ---- P1 compute: rhs = tr@W^T - st ; q = st@W^T ----
    f32x4 rhsF[2], qF[2];
#pragma unroll
    for (int u = 0; u < 2; ++u) {
      f32x4 racc = {0.f, 0.f, 0.f, 0.f}, qacc = {0.f, 0.f, 0.f, 0.f};
#pragma unroll
      for (int k = 0; k < 8; ++k) {
        bf16x8 wb = ldfrag(&WbL[lr][k * 32 + lq * 8]);
        racc = mfma16(asfrag(trR[u][k]), wb, racc);
        qacc = mfma16(asfrag(stR[u][k]), wb, qacc);
      }
#pragma unroll
      for (int r = 0; r < 4; ++r) racc[r] -= sub[u][r];
      rhsF[u] = racc; qF[u] = qacc;
      ushort4 pk;
      pk.x = f2bf(racc.x); pk.y = f2bf(racc.y);
      pk.z = f2bf(racc.z); pk.w = f2bf(racc.w);
      *(ushort4*)(&RpL[w + 8 * u][lr * RP + lq * 4]) = pk;
    }
    __syncthreads();  // b1

    // ---- prefetch LbG frags (used in P4) ----
    uint4 lbRa[4], lbRb[8];
    {
      const u16* lb0 = LbG + ((size_t)(c * 16 + w) * 8) * 512 + lr * 32 + lq * 8;
      const u16* lb1 = lb0 + (size_t)8 * 8 * 512;
#pragma unroll
      for (int sp = 0; sp < 4; ++sp) lbRa[sp] = ldmask(lb0, sp, nL0);
#pragma unroll
      for (int sp = 0; sp < 5; ++sp) lbRb[sp] = *(const uint4*)(lb1 + (size_t)sp * 512);
#pragma unroll
      for (int sp = 5; sp < 8; ++sp) lbRb[sp] = ldmask(lb1, sp, nL1);
    }

    // ---- P2: y1 = A @ rhs ----
    f32x4 y1F[2];
    {
      f32x4 acc = {0.f, 0.f, 0.f, 0.f};
#pragma unroll
      for (int sp = 0; sp < 4; ++sp) {
        bf16x8 bf = ldfrag(&RpL[2 * sp + (lq >> 1)][lr * RP + (lq & 1) * 8]);
        acc = mfma16(asfrag(agRa[sp]), bf, acc);
      }
      y1F[0] = acc;
      ushort4 pk;
      pk.x = f2bf(acc.x); pk.y = f2bf(acc.y);
      pk.z = f2bf(acc.z); pk.w = f2bf(acc.w);
      *(ushort4*)(&Y1L[w][lr * RP + lq * 4]) = pk;
    }
    {
      f32x4 acc = {0.f, 0.f, 0.f, 0.f};
#pragma unroll
      for (int sp = 0; sp < 8; ++sp) {
        bf16x8 bf = ldfrag(&RpL[2 * sp + (lq >> 1)][lr * RP + (lq & 1) * 8]);
        acc = mfma16(asfrag(agRb[sp]), bf, acc);
      }
      y1F[1] = acc;
      ushort4 pk;
      pk.x = f2bf(acc.x); pk.y = f2bf(acc.y);
      pk.z = f2bf(acc.z); pk.w = f2bf(acc.w);
      *(ushort4*)(&Y1L[w + 8][lr * RP + lq * 4]) = pk;
    }
    __syncthreads();  // b2

    // ---- P3: y2 = A @ y1; Dp = -kappa*(rhs - k*y1 + k^2*y2) ----
    {
      f32x4 acc = {0.f, 0.f, 0.f, 0.f};
#pragma unroll
      for (int sp = 0; sp < 4; ++sp) {
        bf16x8 bf = ldfrag(&Y1L[2 * sp + (lq >> 1)][lr * RP + (lq & 1) * 8]);
        acc = mfma16(asfrag(agRa[sp]), bf, acc);
      }
      ushort4 pk;
#pragma unroll
      for (int r = 0; r < 4; ++r) {
        float dv = rhsF[0][r] - KAPPA * y1F[0][r] + (KAPPA * KAPPA) * acc[r];
        ((u16*)&pk)[r] = f2bf(-KAPPA * dv);
      }
      *(ushort4*)(&DpL[w][lr * RP + lq * 4]) = pk;
    }
    {
      f32x4 acc = {0.f, 0.f, 0.f, 0.f};
#pragma unroll
      for (int sp = 0; sp < 8; ++sp) {
        bf16x8 bf = ldfrag(&Y1L[2 * sp + (lq >> 1)][lr * RP + (lq & 1) * 8]);
        acc = mfma16(asfrag(agRb[sp]), bf, acc);
      }
      ushort4 pk;
#pragma unroll
      for (int r = 0; r < 4; ++r) {
        float dv = rhsF[1][r] - KAPPA * y1F[1][r] + (KAPPA * KAPPA) * acc[r];
        ((u16*)&pk)[r] = f2bf(-KAPPA * dv);
      }
      *(ushort4*)(&DpL[w + 8][lr * RP + lq * 4]) = pk;
    }
    __syncthreads();  // b3

    // ---- P4a: Out = q + Lb @ Dp ; plain store ----
    {
      f32x4 acc = qF[0];
#pragma unroll
      for (int sp = 0; sp < 4; ++sp) {
        bf16x8 bf = ldfrag(&DpL[2 * sp + (lq >> 1)][lr * RP + (lq & 1) * 8]);
        acc = mfma16(asfrag(lbRa[sp]), bf, acc);
      }
      const size_t T = (size_t)c * CC + w;
#pragma unroll
      for (int r = 0; r < 4; ++r) {
        size_t oi = ((size_t)(lq * 4 + r) * SS + T) * SD + d1b * 16 + lr;
        out[oi] = acc[r];
      }
    }
    {
      f32x4 acc = qF[1];
#pragma unroll
      for (int sp = 0; sp < 8; ++sp) {
        bf16x8 bf = ldfrag(&DpL[2 * sp + (lq >> 1)][lr * RP + (lq & 1) * 8]);
        acc = mfma16(asfrag(lbRb[sp]), bf, acc);
      }
      const size_t T = (size_t)c * CC + w + 8;
#pragma unroll
      for (int r = 0; r < 4; ++r) {
        size_t oi = ((size_t)(lq * 4 + r) * SS + T) * SD + d1b * 16 + lr;
        out[oi] = acc[r];
      }
    }

    // ---- P4b: dW = Dp^T-stack @ trT ; apply to WfL and WbL ----
    bf16x8 afR[8];
#pragma unroll
    for (int sp = 0; sp < 8; ++sp)
      afR[sp] = ldfrag(&DpL[2 * sp + (lq >> 1)][lr * RP + (lq & 1) * 8]);
#pragma unroll
    for (int u = 0; u < 2; ++u) {
      const int d2b = w + 8 * u;
      f32x4 acc = {0.f, 0.f, 0.f, 0.f};
#pragma unroll
      for (int sp = 0; sp < 8; ++sp) {
        const int s0 = 2 * sp + (lq >> 1);
        bf16x8 bf = ldfrag(trT + ((size_t)(c * CC + s0) * 256 + d2b * 16 + lr) * 16 +
                           (lq & 1) * 8);
        acc = mfma16(afR[sp], bf, acc);
      }
#pragma unroll
      for (int r = 0; r < 4; ++r) {
        float nw = WfL[lq * 4 + r][d2b * 16 + lr] + acc[r];
        WfL[lq * 4 + r][d2b * 16 + lr] = nw;
        WbL[lq * 4 + r][d2b * 16 + lr] = f2bf(nw);
      }
    }

    __syncthreads();  // b4: W ready for next chunk
  }
}

extern "C" void kernel_launch(void* const* d_in, const int* in_sizes, int n_in,
                              void* d_out, int out_size, void* d_ws, size_t ws_size,
                              hipStream_t stream) {
  const float* x     = (const float*)d_in[0];
  const float* noise = (const float*)d_in[1];
  const float* a1    = (const float*)d_in[2];
  const float* a2    = (const float*)d_in[3];
  const float* Wttt  = (const float*)d_in[4];
  const float* Wproj = (const float*)d_in[5];
  const float* ffa   = (const float*)d_in[6];
  const float* ffb   = (const float*)d_in[7];
  const float* ffg   = (const float*)d_in[8];
  const float* ffe   = (const float*)d_in[9];
  float* out = (float*)d_out;

  const size_t N = (size_t)SB * SS * SD;   // 8388608 elements
  u16* tr  = (u16*)d_ws;
  u16* st  = tr + N;
  u16* trT = st + N;
  u16* AG  = trT + N;
  u16* LbG = AG + N;    // total ws = 5N*2B ~ 84MB

  prep_kernel<<<8192, 256, 0, stream>>>(x, noise, a1, tr, st, trT);
  gram2_kernel<<<2048, 256, 0, stream>>>(tr, st, AG, LbG);
  scan_kernel<<<16, 512, 0, stream>>>(tr, st, trT, AG, LbG, Wttt, out);
  ff_kernel<<<dim3(512, 4), 256, 0, stream>>>(x, a2, Wproj, ffa, ffb, ffg, ffe, out);
}

// Round 5
// 1959.539 us; speedup vs baseline: 1.8633x; 1.0372x over previous
//
#include <hip/hip_runtime.h>

typedef unsigned short u16;
typedef unsigned int u32;
typedef __attribute__((ext_vector_type(8))) short bf16x8;
typedef __attribute__((ext_vector_type(4))) float f32x4;

#define SB 16
#define SS 2048
#define SD 256
#define CC 16            // chunk length
#define NCH (SS / CC)    // 128 chunks
#define KAPPA 4.8828125e-6f   // 0.01 * 2/(16*256)
#define RP 24            // u16 pitch of transposed 16x16 publish tiles

__device__ __forceinline__ u16 f2bf(float f) {
  u32 u = __float_as_uint(f);
  u = (u + 0x7FFFu + ((u >> 16) & 1u)) >> 16;
  return (u16)u;
}
__device__ __forceinline__ float bf2f(u16 u) { return __uint_as_float((u32)u << 16); }

__device__ __forceinline__ bf16x8 ldfrag(const u16* p) {
  union { uint4 u; bf16x8 f; } cv;
  cv.u = *(const uint4*)p;
  return cv.f;
}
__device__ __forceinline__ bf16x8 asfrag(uint4 q) {
  union { uint4 u; bf16x8 f; } cv;
  cv.u = q;
  return cv.f;
}
__device__ __forceinline__ f32x4 mfma16(bf16x8 a, bf16x8 b, f32x4 c) {
  return __builtin_amdgcn_mfma_f32_16x16x32_bf16(a, b, c, 0, 0, 0);
}

// ---------------- prep: train/state (bf16 [t][b][d]) + trainT ([t][d][b]) ----
__global__ __launch_bounds__(256) void prep_kernel(
    const float* __restrict__ x, const float* __restrict__ noise,
    const float* __restrict__ a1,
    u16* __restrict__ train, u16* __restrict__ state, u16* __restrict__ trainT) {
  size_t i4 = (size_t)blockIdx.x * 256 + threadIdx.x;
  size_t base = i4 * 4;
  int d = (int)(base & 255);
  int t = (int)((base >> 8) & 2047);
  int b = (int)(base >> 19);
  float4 xv = *(const float4*)(x + base);
  float4 nv = *(const float4*)(noise + base);
  float4 av = *(const float4*)(a1 + d);
  float m0 = tanhf(av.x * xv.x);
  float m1 = tanhf(av.y * xv.y);
  float m2 = tanhf(av.z * xv.z);
  float m3 = tanhf(av.w * xv.w);
  size_t dst = ((size_t)t * SB + b) * SD + d;
  ushort4 tr, st;
  tr.x = f2bf(m0 + nv.x); tr.y = f2bf(m1 + nv.y);
  tr.z = f2bf(m2 + nv.z); tr.w = f2bf(m3 + nv.w);
  st.x = f2bf(m0); st.y = f2bf(m1); st.z = f2bf(m2); st.w = f2bf(m3);
  *(ushort4*)(train + dst) = tr;
  *(ushort4*)(state + dst) = st;
  size_t tb = ((size_t)t * SD + d) * SB + b;   // trainT[t][d][b]
  trainT[tb + 0 * SB] = tr.x;
  trainT[tb + 1 * SB] = tr.y;
  trainT[tb + 2 * SB] = tr.z;
  trainT[tb + 3 * SB] = tr.w;
}

// ---------------- fused: gram2 (blocks 0..2047) || ff' (blocks 2048..4095) --
// gram2: AG[c][t][sp][16][32], LbG likewise (zero-filled).
// ff':   out = u .* (v @ Wp^T)   (NO prev add -- scan adds its result later;
//        MFMA-pipe gram2 and VALU-pipe ff co-schedule on shared CUs).
__global__ __launch_bounds__(256) void gram2ff_kernel(
    const u16* __restrict__ tr, const u16* __restrict__ st,
    u16* __restrict__ AG, u16* __restrict__ LbG,
    const float* __restrict__ x, const float* __restrict__ a2,
    const float* __restrict__ Wp, const float* __restrict__ ffa,
    const float* __restrict__ ffb, const float* __restrict__ ffg_,
    const float* __restrict__ ffe_, float* __restrict__ out) {
  __shared__ float As[32][68];
  __shared__ float Bs[32][68];
  const int tid = threadIdx.x;

  if (blockIdx.x < 2048) {
    // ---------------- gram2 body (unchanged) ----------------
    const int cb = blockIdx.x;        // c*16 + t
    const int c = cb >> 4, t = cb & 15;
    const int lane = tid & 63, wv = tid >> 6;
    const int lr = lane & 15, lq = lane >> 4;
    const size_t Tt = (size_t)cb;
    bf16x8 trF[8], stF[8];
#pragma unroll
    for (int k = 0; k < 8; ++k) {
      trF[k] = ldfrag(tr + (Tt * 16 + lr) * 256 + k * 32 + lq * 8);
      stF[k] = ldfrag(st + (Tt * 16 + lr) * 256 + k * 32 + lq * 8);
    }
    for (int ii = 0; ii < 2; ++ii) {
      const int sp = wv + ii * 4;
      u16* dA = AG + ((size_t)cb * 8 + sp) * 512;
      u16* dL = LbG + ((size_t)cb * 8 + sp) * 512;
#pragma unroll
      for (int h = 0; h < 2; ++h) {
        const int s = 2 * sp + h;
        f32x4 accA = {0.f, 0.f, 0.f, 0.f}, accL = {0.f, 0.f, 0.f, 0.f};
        if (s <= t) {
          const u16* bsrc = tr + ((size_t)(c * 16 + s) * 16 + lr) * 256 + lq * 8;
#pragma unroll
          for (int k = 0; k < 8; ++k) {
            bf16x8 bk = ldfrag(bsrc + k * 32);
            if (s < t) accA = mfma16(trF[k], bk, accA);
            accL = mfma16(stF[k], bk, accL);
          }
        }
#pragma unroll
        for (int r = 0; r < 4; ++r) {
          int idx = (lq * 4 + r) * 32 + h * 16 + lr;
          dA[idx] = (s < t) ? f2bf(accA[r]) : (u16)0;
          dL[idx] = (s <= t) ? f2bf(accL[r]) : (u16)0;
        }
      }
    }
    return;
  }

  // ---------------- ff' body ----------------
  const int fb = blockIdx.x - 2048;
  const int gm0 = (fb >> 2) * 64;
  const int gn0 = (fb & 3) * 64;
  const int tm = tid & 15, tn = tid >> 4;
  const int lr = tid & 63;
  const int lq = tid >> 6;
  float acc[4][4];
#pragma unroll
  for (int i = 0; i < 4; i++)
#pragma unroll
    for (int j = 0; j < 4; j++) acc[i][j] = 0.f;

  for (int k0 = 0; k0 < 256; k0 += 32) {
    {
      const float* xp = x + (size_t)(gm0 + lr) * 256 + k0 + lq * 8;
      float4 v0 = *(const float4*)(xp);
      float4 v1 = *(const float4*)(xp + 4);
      const float* ap = a2 + k0 + lq * 8;
      float4 a0 = *(const float4*)(ap);
      float4 a1v = *(const float4*)(ap + 4);
      As[lq * 8 + 0][lr] = tanhf(a0.x * v0.x);
      As[lq * 8 + 1][lr] = tanhf(a0.y * v0.y);
      As[lq * 8 + 2][lr] = tanhf(a0.z * v0.z);
      As[lq * 8 + 3][lr] = tanhf(a0.w * v0.w);
      As[lq * 8 + 4][lr] = tanhf(a1v.x * v1.x);
      As[lq * 8 + 5][lr] = tanhf(a1v.y * v1.y);
      As[lq * 8 + 6][lr] = tanhf(a1v.z * v1.z);
      As[lq * 8 + 7][lr] = tanhf(a1v.w * v1.w);
      const float* wp = Wp + (size_t)(gn0 + lr) * 256 + k0 + lq * 8;
      float4 w0 = *(const float4*)(wp);
      float4 w1 = *(const float4*)(wp + 4);
      Bs[lq * 8 + 0][lr] = w0.x; Bs[lq * 8 + 1][lr] = w0.y;
      Bs[lq * 8 + 2][lr] = w0.z; Bs[lq * 8 + 3][lr] = w0.w;
      Bs[lq * 8 + 4][lr] = w1.x; Bs[lq * 8 + 5][lr] = w1.y;
      Bs[lq * 8 + 6][lr] = w1.z; Bs[lq * 8 + 7][lr] = w1.w;
    }
    __syncthreads();
#pragma unroll
    for (int k = 0; k < 32; ++k) {
      float4 av4 = *(const float4*)&As[k][tm * 4];
      float4 bv4 = *(const float4*)&Bs[k][tn * 4];
      float a[4] = {av4.x, av4.y, av4.z, av4.w};
      float b[4] = {bv4.x, bv4.y, bv4.z, bv4.w};
#pragma unroll
      for (int i = 0; i < 4; i++)
#pragma unroll
        for (int j = 0; j < 4; j++) acc[i][j] += a[i] * b[j];
    }
    __syncthreads();
  }
  const float ga = ffg_[0], et = ffe_[0];
#pragma unroll
  for (int ii = 0; ii < 4; ++ii) {
    int row = gm0 + tm * 4 + ii;
    int col = gn0 + tn * 4;
    float4 xv = *(const float4*)(x + (size_t)row * 256 + col);
    float4 fa = *(const float4*)(ffa + col);
    float4 fb4 = *(const float4*)(ffb + col);
    float4 a2v = *(const float4*)(a2 + col);
    float xs[4] = {xv.x, xv.y, xv.z, xv.w};
    float fas[4] = {fa.x, fa.y, fa.z, fa.w};
    float fbs[4] = {fb4.x, fb4.y, fb4.z, fb4.w};
    float a2s[4] = {a2v.x, a2v.y, a2v.z, a2v.w};
    float res[4];
#pragma unroll
    for (int j = 0; j < 4; ++j) {
      float v = tanhf(a2s[j] * xs[j]);
      float z = fas[j] * v;
      float gelu = 0.5f * z * (1.0f + erff(z * 0.70710678118654752f));
      float u = ga * gelu + et * sinf(fbs[j] * v);
      res[j] = u * acc[ii][j];
    }
    float4 o; o.x = res[0]; o.y = res[1]; o.z = res[2]; o.w = res[3];
    *(float4*)(out + (size_t)row * 256 + col) = o;
  }
}

// ---------------- scan: 16 WGs x 512 thr; wave w owns t=w and t=w+8 --------
// 3-phase variant of the R0 structure.  The kappa^2*y2 Neumann term is
// dropped (relative contribution ~1e-6, far below the bf16 publish
// rounding already present), which deletes phase P3 and one barrier:
//   P1: rhs,q -> b1 -> P2': Dp = -k*(rhs - k*A@rhs) -> b2 -> P4 -> b3.
// All loads phase-local and unconditional (R0's proven codegen pattern).
// P4a now ADDS the ff path's g (pre-written into out by gram2ff).
__global__ __launch_bounds__(512, 1) void scan_kernel(
    const u16* __restrict__ tr, const u16* __restrict__ st,
    const u16* __restrict__ trT, const u16* __restrict__ AG,
    const u16* __restrict__ LbG, const float* __restrict__ Wttt,
    float* __restrict__ out) {
  __shared__ u16 RpL[CC][16 * RP];   // bf16(rhs) transposed [d1][b]
  __shared__ u16 DpL[CC][16 * RP];
  __shared__ u16 WbL[16][268];       // bf16 W block [d1][d], pitch 268
  __shared__ float WfL[16][268];     // f32 master

  const int tid = threadIdx.x;
  const int lane = tid & 63;
  const int w = tid >> 6;            // wave 0..7
  const int d1b = blockIdx.x;
  const int lr = lane & 15;
  const int lq = lane >> 4;

  for (int i = tid; i < 16 * 256; i += 512) {
    int r = i >> 8, d = i & 255;
    float wv_ = Wttt[(size_t)(d1b * 16 + r) * 256 + d];
    WfL[r][d] = wv_;
    WbL[r][d] = f2bf(wv_);
  }
  __syncthreads();

  for (int c = 0; c < NCH; ++c) {
    // ---- prefetch AG frags for both t's (used in P2') ----
    uint4 agR[2][8];
#pragma unroll
    for (int u = 0; u < 2; ++u) {
      const u16* ag = AG + ((size_t)(c * 16 + w + 8 * u) * 8) * 512 + lr * 32 + lq * 8;
#pragma unroll
      for (int sp = 0; sp < 8; ++sp) agR[u][sp] = *(const uint4*)(ag + sp * 512);
    }
    // ---- P1 loads: tr/st frags + st scalars for both t's ----
    uint4 trR[2][8], stR[2][8];
    float sub[2][4];
#pragma unroll
    for (int u = 0; u < 2; ++u) {
      const size_t T = (size_t)c * CC + w + 8 * u;
      const u16* trt = tr + (T * 16 + lr) * 256 + lq * 8;
      const u16* stt = st + (T * 16 + lr) * 256 + lq * 8;
#pragma unroll
      for (int k = 0; k < 8; ++k) {
        trR[u][k] = *(const uint4*)(trt + k * 32);
        stR[u][k] = *(const uint4*)(stt + k * 32);
      }
#pragma unroll
      for (int r = 0; r < 4; ++r)
        sub[u][r] = bf2f(st[(T * 16 + lq * 4 + r) * 256 + d1b * 16 + lr]);
    }

    // ---- P1 compute: rhs = tr@W^T - st ; q = st@W^T ----
    f32x4 rhsF[2], qF[2];
#pragma unroll
    for (int u = 0; u < 2; ++u) {
      f32x4 racc = {0.f, 0.f, 0.f, 0.f}, qacc = {0.f, 0.f, 0.f, 0.f};
#pragma unroll
      for (int k = 0; k < 8; ++k) {
        bf16x8 wb = ldfrag(&WbL[lr][k * 32 + lq * 8]);
        racc = mfma16(asfrag(trR[u][k]), wb, racc);
        qacc = mfma16(asfrag(stR[u][k]), wb, qacc);
      }
#pragma unroll
      for (int r = 0; r < 4; ++r) racc[r] -= sub[u][r];
      rhsF[u] = racc; qF[u] = qacc;
      ushort4 pk;
      pk.x = f2bf(racc.x); pk.y = f2bf(racc.y);
      pk.z = f2bf(racc.z); pk.w = f2bf(racc.w);
      *(ushort4*)(&RpL[w + 8 * u][lr * RP + lq * 4]) = pk;
    }
    __syncthreads();  // b1

    // ---- prefetch LbG frags (used in P4) ----
    uint4 lbR[2][8];
#pragma unroll
    for (int u = 0; u < 2; ++u) {
      const u16* lb = LbG + ((size_t)(c * 16 + w + 8 * u) * 8) * 512 + lr * 32 + lq * 8;
#pragma unroll
      for (int sp = 0; sp < 8; ++sp) lbR[u][sp] = *(const uint4*)(lb + sp * 512);
    }

    // ---- P2': z = A @ rhs ; Dp = -k*(rhs - k*z) ; publish ----
#pragma unroll
    for (int u = 0; u < 2; ++u) {
      f32x4 acc = {0.f, 0.f, 0.f, 0.f};
#pragma unroll
      for (int sp = 0; sp < 8; ++sp) {
        bf16x8 bf = ldfrag(&RpL[2 * sp + (lq >> 1)][lr * RP + (lq & 1) * 8]);
        acc = mfma16(asfrag(agR[u][sp]), bf, acc);
      }
      ushort4 pk;
#pragma unroll
      for (int r = 0; r < 4; ++r) {
        float dv = rhsF[u][r] - KAPPA * acc[r];
        ((u16*)&pk)[r] = f2bf(-KAPPA * dv);
      }
      *(ushort4*)(&DpL[w + 8 * u][lr * RP + lq * 4]) = pk;
    }
    __syncthreads();  // b2

    // ---- P4 loads: trT frags + g (ff path) previously written to out ----
    uint4 trTR[2][8];
    float gp[2][4];
#pragma unroll
    for (int u = 0; u < 2; ++u) {
      const int d2b = w + 8 * u;
#pragma unroll
      for (int sp = 0; sp < 8; ++sp) {
        const int s0 = 2 * sp + (lq >> 1);
        trTR[u][sp] = *(const uint4*)(trT +
            ((size_t)(c * CC + s0) * 256 + d2b * 16 + lr) * 16 + (lq & 1) * 8);
      }
      const size_t T = (size_t)c * CC + w + 8 * u;
#pragma unroll
      for (int r = 0; r < 4; ++r)
        gp[u][r] = out[((size_t)(lq * 4 + r) * SS + T) * SD + d1b * 16 + lr];
    }

    // ---- P4a: Out = g + q + Lb @ Dp ----
#pragma unroll
    for (int u = 0; u < 2; ++u) {
      const size_t T = (size_t)c * CC + w + 8 * u;
      f32x4 acc = qF[u];
#pragma unroll
      for (int sp = 0; sp < 8; ++sp) {
        bf16x8 bf = ldfrag(&DpL[2 * sp + (lq >> 1)][lr * RP + (lq & 1) * 8]);
        acc = mfma16(asfrag(lbR[u][sp]), bf, acc);
      }
#pragma unroll
      for (int r = 0; r < 4; ++r) {
        size_t oi = ((size_t)(lq * 4 + r) * SS + T) * SD + d1b * 16 + lr;
        out[oi] = acc[r] + gp[u][r];
      }
    }

    // ---- P4b: dW = Dp^T-stack @ trT ; apply to WfL and WbL ----
    bf16x8 afR[8];
#pragma unroll
    for (int sp = 0; sp < 8; ++sp)
      afR[sp] = ldfrag(&DpL[2 * sp + (lq >> 1)][lr * RP + (lq & 1) * 8]);
#pragma unroll
    for (int u = 0; u < 2; ++u) {
      const int d2b = w + 8 * u;
      f32x4 acc = {0.f, 0.f, 0.f, 0.f};
#pragma unroll
      for (int sp = 0; sp < 8; ++sp)
        acc = mfma16(afR[sp], asfrag(trTR[u][sp]), acc);
#pragma unroll
      for (int r = 0; r < 4; ++r) {
        float nw = WfL[lq * 4 + r][d2b * 16 + lr] + acc[r];
        WfL[lq * 4 + r][d2b * 16 + lr] = nw;
        WbL[lq * 4 + r][d2b * 16 + lr] = f2bf(nw);
      }
    }
    __syncthreads();  // b3: W ready for next chunk
  }
}

extern "C" void kernel_launch(void* const* d_in, const int* in_sizes, int n_in,
                              void* d_out, int out_size, void* d_ws, size_t ws_size,
                              hipStream_t stream) {
  const float* x     = (const float*)d_in[0];
  const float* noise = (const float*)d_in[1];
  const float* a1    = (const float*)d_in[2];
  const float* a2    = (const float*)d_in[3];
  const float* Wttt  = (const float*)d_in[4];
  const float* Wproj = (const float*)d_in[5];
  const float* ffa   = (const float*)d_in[6];
  const float* ffb   = (const float*)d_in[7];
  const float* ffg   = (const float*)d_in[8];
  const float* ffe   = (const float*)d_in[9];
  float* out = (float*)d_out;

  const size_t N = (size_t)SB * SS * SD;   // 8388608 elements
  u16* tr  = (u16*)d_ws;
  u16* st  = tr + N;
  u16* trT = st + N;
  u16* AG  = trT + N;
  u16* LbG = AG + N;    // total ws = 5N*2B ~ 84MB

  prep_kernel<<<8192, 256, 0, stream>>>(x, noise, a1, tr, st, trT);
  gram2ff_kernel<<<4096, 256, 0, stream>>>(tr, st, AG, LbG,
                                           x, a2, Wproj, ffa, ffb, ffg, ffe, out);
  scan_kernel<<<16, 512, 0, stream>>>(tr, st, trT, AG, LbG, Wttt, out);
}

// Round 6
// 873.806 us; speedup vs baseline: 4.1786x; 2.2425x over previous
//
#include <hip/hip_runtime.h>

typedef unsigned short u16;
typedef unsigned int u32;
typedef __attribute__((ext_vector_type(8))) short bf16x8;
typedef __attribute__((ext_vector_type(4))) float f32x4;

#define SB 16
#define SS 2048
#define SD 256
#define CC 16            // chunk length
#define NCH (SS / CC)    // 128 chunks
#define KAPPA 4.8828125e-6f   // 0.01 * 2/(16*256)
#define RP 24            // u16 pitch of transposed 16x16 publish tiles
#define SLOT 65536       // elements per [256,256] transfer slot

__device__ __forceinline__ u16 f2bf(float f) {
  u32 u = __float_as_uint(f);
  u = (u + 0x7FFFu + ((u >> 16) & 1u)) >> 16;
  return (u16)u;
}
__device__ __forceinline__ float bf2f(u16 u) { return __uint_as_float((u32)u << 16); }

__device__ __forceinline__ bf16x8 ldfrag(const u16* p) {
  union { uint4 u; bf16x8 f; } cv;
  cv.u = *(const uint4*)p;
  return cv.f;
}
__device__ __forceinline__ bf16x8 asfrag(uint4 q) {
  union { uint4 u; bf16x8 f; } cv;
  cv.u = q;
  return cv.f;
}
__device__ __forceinline__ f32x4 mfma16(bf16x8 a, bf16x8 b, f32x4 c) {
  return __builtin_amdgcn_mfma_f32_16x16x32_bf16(a, b, c, 0, 0, 0);
}

// ---------------- prep: train/state (bf16 [t][b][d]) + trainT ([t][d][b]) ----
__global__ __launch_bounds__(256) void prep_kernel(
    const float* __restrict__ x, const float* __restrict__ noise,
    const float* __restrict__ a1,
    u16* __restrict__ train, u16* __restrict__ state, u16* __restrict__ trainT) {
  size_t i4 = (size_t)blockIdx.x * 256 + threadIdx.x;
  size_t base = i4 * 4;
  int d = (int)(base & 255);
  int t = (int)((base >> 8) & 2047);
  int b = (int)(base >> 19);
  float4 xv = *(const float4*)(x + base);
  float4 nv = *(const float4*)(noise + base);
  float4 av = *(const float4*)(a1 + d);
  float m0 = tanhf(av.x * xv.x);
  float m1 = tanhf(av.y * xv.y);
  float m2 = tanhf(av.z * xv.z);
  float m3 = tanhf(av.w * xv.w);
  size_t dst = ((size_t)t * SB + b) * SD + d;
  ushort4 tr, st;
  tr.x = f2bf(m0 + nv.x); tr.y = f2bf(m1 + nv.y);
  tr.z = f2bf(m2 + nv.z); tr.w = f2bf(m3 + nv.w);
  st.x = f2bf(m0); st.y = f2bf(m1); st.z = f2bf(m2); st.w = f2bf(m3);
  *(ushort4*)(train + dst) = tr;
  *(ushort4*)(state + dst) = st;
  size_t tb = ((size_t)t * SD + d) * SB + b;   // trainT[t][d][b]
  trainT[tb + 0 * SB] = tr.x;
  trainT[tb + 1 * SB] = tr.y;
  trainT[tb + 2 * SB] = tr.z;
  trainT[tb + 3 * SB] = tr.w;
}

// ---------------- fused: gram2 (blocks 0..2047) || ff' (blocks 2048..4095) --
__global__ __launch_bounds__(256) void gram2ff_kernel(
    const u16* __restrict__ tr, const u16* __restrict__ st,
    u16* __restrict__ AG, u16* __restrict__ LbG,
    const float* __restrict__ x, const float* __restrict__ a2,
    const float* __restrict__ Wp, const float* __restrict__ ffa,
    const float* __restrict__ ffb, const float* __restrict__ ffg_,
    const float* __restrict__ ffe_, float* __restrict__ out) {
  __shared__ float As[32][68];
  __shared__ float Bs[32][68];
  const int tid = threadIdx.x;

  if (blockIdx.x < 2048) {
    const int cb = blockIdx.x;        // c*16 + t
    const int c = cb >> 4, t = cb & 15;
    const int lane = tid & 63, wv = tid >> 6;
    const int lr = lane & 15, lq = lane >> 4;
    const size_t Tt = (size_t)cb;
    bf16x8 trF[8], stF[8];
#pragma unroll
    for (int k = 0; k < 8; ++k) {
      trF[k] = ldfrag(tr + (Tt * 16 + lr) * 256 + k * 32 + lq * 8);
      stF[k] = ldfrag(st + (Tt * 16 + lr) * 256 + k * 32 + lq * 8);
    }
    for (int ii = 0; ii < 2; ++ii) {
      const int sp = wv + ii * 4;
      u16* dA = AG + ((size_t)cb * 8 + sp) * 512;
      u16* dL = LbG + ((size_t)cb * 8 + sp) * 512;
#pragma unroll
      for (int h = 0; h < 2; ++h) {
        const int s = 2 * sp + h;
        f32x4 accA = {0.f, 0.f, 0.f, 0.f}, accL = {0.f, 0.f, 0.f, 0.f};
        if (s <= t) {
          const u16* bsrc = tr + ((size_t)(c * 16 + s) * 16 + lr) * 256 + lq * 8;
#pragma unroll
          for (int k = 0; k < 8; ++k) {
            bf16x8 bk = ldfrag(bsrc + k * 32);
            if (s < t) accA = mfma16(trF[k], bk, accA);
            accL = mfma16(stF[k], bk, accL);
          }
        }
#pragma unroll
        for (int r = 0; r < 4; ++r) {
          int idx = (lq * 4 + r) * 32 + h * 16 + lr;
          dA[idx] = (s < t) ? f2bf(accA[r]) : (u16)0;
          dL[idx] = (s <= t) ? f2bf(accL[r]) : (u16)0;
        }
      }
    }
    return;
  }

  // ---------------- ff' body: out = u .* (v @ Wp^T)  (no prev add) --------
  const int fb = blockIdx.x - 2048;
  const int gm0 = (fb >> 2) * 64;
  const int gn0 = (fb & 3) * 64;
  const int tm = tid & 15, tn = tid >> 4;
  const int lr = tid & 63;
  const int lq = tid >> 6;
  float acc[4][4];
#pragma unroll
  for (int i = 0; i < 4; i++)
#pragma unroll
    for (int j = 0; j < 4; j++) acc[i][j] = 0.f;

  for (int k0 = 0; k0 < 256; k0 += 32) {
    {
      const float* xp = x + (size_t)(gm0 + lr) * 256 + k0 + lq * 8;
      float4 v0 = *(const float4*)(xp);
      float4 v1 = *(const float4*)(xp + 4);
      const float* ap = a2 + k0 + lq * 8;
      float4 a0 = *(const float4*)(ap);
      float4 a1v = *(const float4*)(ap + 4);
      As[lq * 8 + 0][lr] = tanhf(a0.x * v0.x);
      As[lq * 8 + 1][lr] = tanhf(a0.y * v0.y);
      As[lq * 8 + 2][lr] = tanhf(a0.z * v0.z);
      As[lq * 8 + 3][lr] = tanhf(a0.w * v0.w);
      As[lq * 8 + 4][lr] = tanhf(a1v.x * v1.x);
      As[lq * 8 + 5][lr] = tanhf(a1v.y * v1.y);
      As[lq * 8 + 6][lr] = tanhf(a1v.z * v1.z);
      As[lq * 8 + 7][lr] = tanhf(a1v.w * v1.w);
      const float* wp = Wp + (size_t)(gn0 + lr) * 256 + k0 + lq * 8;
      float4 w0 = *(const float4*)(wp);
      float4 w1 = *(const float4*)(wp + 4);
      Bs[lq * 8 + 0][lr] = w0.x; Bs[lq * 8 + 1][lr] = w0.y;
      Bs[lq * 8 + 2][lr] = w0.z; Bs[lq * 8 + 3][lr] = w0.w;
      Bs[lq * 8 + 4][lr] = w1.x; Bs[lq * 8 + 5][lr] = w1.y;
      Bs[lq * 8 + 6][lr] = w1.z; Bs[lq * 8 + 7][lr] = w1.w;
    }
    __syncthreads();
#pragma unroll
    for (int k = 0; k < 32; ++k) {
      float4 av4 = *(const float4*)&As[k][tm * 4];
      float4 bv4 = *(const float4*)&Bs[k][tn * 4];
      float a[4] = {av4.x, av4.y, av4.z, av4.w};
      float b[4] = {bv4.x, bv4.y, bv4.z, bv4.w};
#pragma unroll
      for (int i = 0; i < 4; i++)
#pragma unroll
        for (int j = 0; j < 4; j++) acc[i][j] += a[i] * b[j];
    }
    __syncthreads();
  }
  const float ga = ffg_[0], et = ffe_[0];
#pragma unroll
  for (int ii = 0; ii < 4; ++ii) {
    int row = gm0 + tm * 4 + ii;
    int col = gn0 + tn * 4;
    float4 xv = *(const float4*)(x + (size_t)row * 256 + col);
    float4 fa = *(const float4*)(ffa + col);
    float4 fb4 = *(const float4*)(ffb + col);
    float4 a2v = *(const float4*)(a2 + col);
    float xs[4] = {xv.x, xv.y, xv.z, xv.w};
    float fas[4] = {fa.x, fa.y, fa.z, fa.w};
    float fbs[4] = {fb4.x, fb4.y, fb4.z, fb4.w};
    float a2s[4] = {a2v.x, a2v.y, a2v.z, a2v.w};
    float res[4];
#pragma unroll
    for (int j = 0; j < 4; ++j) {
      float v = tanhf(a2s[j] * xs[j]);
      float z = fas[j] * v;
      float gelu = 0.5f * z * (1.0f + erff(z * 0.70710678118654752f));
      float u = ga * gelu + et * sinf(fbs[j] * v);
      res[j] = u * acc[ii][j];
    }
    float4 o; o.x = res[0]; o.y = res[1]; o.z = res[2]; o.w = res[3];
    *(float4*)(out + (size_t)row * 256 + col) = o;
  }
}

// ---------------- phase A: per-chunk transfer (Dt transposed, Q normal) ----
// D_c = -k*Sum_t Ytil_t^T X_t, Ytil = X - k*(A@X);  Q_c = +k*Sum_t Ztil_t^T X_t,
// Ztil = st - k*(A@st).  Identical 2nd-order structure to the old P4b dW.
// Grid dim3(16,128): blockIdx.x = d1b (D-row block), blockIdx.y = c.
__global__ __launch_bounds__(512) void phaseA_kernel(
    const u16* __restrict__ tr, const u16* __restrict__ st,
    const u16* __restrict__ trT, const u16* __restrict__ AG,
    u16* __restrict__ Dt, u16* __restrict__ Qb) {
  __shared__ u16 StT[CC][16 * RP];
  __shared__ u16 YtL[CC][16 * RP];
  __shared__ u16 ZtL[CC][16 * RP];
  const int tid = threadIdx.x;
  const int lane = tid & 63;
  const int w = tid >> 6;
  const int d1b = blockIdx.x;
  const int c = blockIdx.y;
  const int lr = lane & 15;
  const int lq = lane >> 4;

  // AG frags for t=w, w+8
  uint4 agR[2][8];
#pragma unroll
  for (int u = 0; u < 2; ++u) {
    const u16* ag = AG + ((size_t)(c * 16 + w + 8 * u) * 8) * 512 + lr * 32 + lq * 8;
#pragma unroll
    for (int sp = 0; sp < 8; ++sp) agR[u][sp] = *(const uint4*)(ag + sp * 512);
  }
  // transposed scalars of tr and st, publish StT
  u16 sraw[2][4];
  float xs[2][4];
#pragma unroll
  for (int u = 0; u < 2; ++u) {
    const size_t T = (size_t)c * CC + w + 8 * u;
    ushort4 pk;
#pragma unroll
    for (int r = 0; r < 4; ++r) {
      size_t idx = (T * 16 + lq * 4 + r) * 256 + d1b * 16 + lr;
      sraw[u][r] = st[idx];
      xs[u][r] = bf2f(tr[idx]);
      ((u16*)&pk)[r] = sraw[u][r];
    }
    *(ushort4*)(&StT[w + 8 * u][lr * RP + lq * 4]) = pk;
  }
  __syncthreads();  // StT ready

  // AX = A@X (via trT), ASt = A@st (via StT); publish Ytil^T, Ztil^T
#pragma unroll
  for (int u = 0; u < 2; ++u) {
    f32x4 a1 = {0.f, 0.f, 0.f, 0.f}, a2 = {0.f, 0.f, 0.f, 0.f};
#pragma unroll
    for (int sp = 0; sp < 8; ++sp) {
      const int s0 = 2 * sp + (lq >> 1);
      bf16x8 xb = ldfrag(trT + ((size_t)(c * CC + s0) * 256 + d1b * 16 + lr) * 16 +
                         (lq & 1) * 8);
      bf16x8 sb = ldfrag(&StT[s0][lr * RP + (lq & 1) * 8]);
      a1 = mfma16(asfrag(agR[u][sp]), xb, a1);
      a2 = mfma16(asfrag(agR[u][sp]), sb, a2);
    }
    ushort4 py, pz;
#pragma unroll
    for (int r = 0; r < 4; ++r) {
      ((u16*)&py)[r] = f2bf(xs[u][r] - KAPPA * a1[r]);
      ((u16*)&pz)[r] = f2bf(bf2f(sraw[u][r]) - KAPPA * a2[r]);
    }
    *(ushort4*)(&YtL[w + 8 * u][lr * RP + lq * 4]) = py;
    *(ushort4*)(&ZtL[w + 8 * u][lr * RP + lq * 4]) = pz;
  }
  __syncthreads();  // Ytil/Ztil ready

  // D/Q gram: P4b-clone.  Output D rows d1b-block x cols d2b (2 per wave).
  bf16x8 yf[8], zf[8];
#pragma unroll
  for (int sp = 0; sp < 8; ++sp) {
    yf[sp] = ldfrag(&YtL[2 * sp + (lq >> 1)][lr * RP + (lq & 1) * 8]);
    zf[sp] = ldfrag(&ZtL[2 * sp + (lq >> 1)][lr * RP + (lq & 1) * 8]);
  }
  const size_t base = (size_t)c * SLOT;
#pragma unroll
  for (int u = 0; u < 2; ++u) {
    const int d2b = w + 8 * u;
    f32x4 da = {0.f, 0.f, 0.f, 0.f}, qa = {0.f, 0.f, 0.f, 0.f};
#pragma unroll
    for (int sp = 0; sp < 8; ++sp) {
      bf16x8 xb = ldfrag(trT + ((size_t)(c * CC + 2 * sp + (lq >> 1)) * 256 +
                                d2b * 16 + lr) * 16 + (lq & 1) * 8);
      da = mfma16(yf[sp], xb, da);
      qa = mfma16(zf[sp], xb, qa);
    }
#pragma unroll
    for (int r = 0; r < 4; ++r) {
      // Dt transposed: [d2][d1]
      Dt[base + (size_t)(d2b * 16 + lr) * 256 + d1b * 16 + lq * 4 + r] =
          f2bf(-KAPPA * da[r]);
      // Q normal: [d1][d2]
      Qb[base + (size_t)(d1b * 16 + lq * 4 + r) * 256 + d2b * 16 + lr] =
          f2bf(KAPPA * qa[r]);
    }
  }
}

// ---------------- Sklansky level: Q update (must run BEFORE D update) ------
// Q_i'' = Q_j + Q_i + Q_j@D_i.  In-place safe: writes own rows/cols of Q_i,
// reads read-only slot j and untouched Dt_i.
__global__ __launch_bounds__(512) void kq_kernel(
    const u16* __restrict__ Dt, u16* __restrict__ Qb, int lev) {
  const int qn = blockIdx.x >> 4, rb = blockIdx.x & 15;
  const int half = 1 << (lev - 1);
  const int blk = qn >> (lev - 1), win = qn & (half - 1);
  const int i = blk * half * 2 + half + win;
  const int j = blk * half * 2 + half - 1;
  u16* Qi = Qb + (size_t)i * SLOT;
  const u16* Qj = Qb + (size_t)j * SLOT;
  const u16* Dti = Dt + (size_t)i * SLOT;
  const int lane = threadIdx.x & 63, w = threadIdx.x >> 6;
  const int lr = lane & 15, lq = lane >> 4;
  bf16x8 aq[8];
#pragma unroll
  for (int kb = 0; kb < 8; ++kb)
    aq[kb] = ldfrag(Qj + (size_t)(rb * 16 + lr) * 256 + kb * 32 + lq * 8);
#pragma unroll
  for (int u = 0; u < 2; ++u) {
    const int cb = w + 8 * u;
    f32x4 acc = {0.f, 0.f, 0.f, 0.f};
#pragma unroll
    for (int kb = 0; kb < 8; ++kb) {
      bf16x8 bf = ldfrag(Dti + (size_t)(cb * 16 + lr) * 256 + kb * 32 + lq * 8);
      acc = mfma16(aq[kb], bf, acc);
    }
#pragma unroll
    for (int r = 0; r < 4; ++r) {
      size_t idx = (size_t)(rb * 16 + lq * 4 + r) * 256 + cb * 16 + lr;
      float v = acc[r] + bf2f(Qj[idx]) + bf2f(Qi[idx]);
      Qi[idx] = f2bf(v);
    }
  }
}

// ---------------- Sklansky level: Dt update --------------------------------
// Dt_i'' = Dt_j + Dt_i + Dt_i@Dt_j  (== transpose of D_j + D_i + D_j@D_i).
// A-operand reads Dt_i across ALL columns -> barrier before any store
// (other waves write other column-blocks of the same rows).
__global__ __launch_bounds__(512) void kd_kernel(u16* __restrict__ Dt, int lev) {
  const int qn = blockIdx.x >> 4, rb = blockIdx.x & 15;
  const int half = 1 << (lev - 1);
  const int blk = qn >> (lev - 1), win = qn & (half - 1);
  const int i = blk * half * 2 + half + win;
  const int j = blk * half * 2 + half - 1;
  u16* Dti = Dt + (size_t)i * SLOT;
  const u16* Dtj = Dt + (size_t)j * SLOT;
  const int lane = threadIdx.x & 63, w = threadIdx.x >> 6;
  const int lr = lane & 15, lq = lane >> 4;
  bf16x8 ad[8];
#pragma unroll
  for (int kb = 0; kb < 8; ++kb)
    ad[kb] = ldfrag(Dti + (size_t)(rb * 16 + lr) * 256 + kb * 32 + lq * 8);
  float oldv[2][4];
#pragma unroll
  for (int u = 0; u < 2; ++u) {
    const int cb = w + 8 * u;
#pragma unroll
    for (int r = 0; r < 4; ++r) {
      size_t idx = (size_t)(rb * 16 + lq * 4 + r) * 256 + cb * 16 + lr;
      oldv[u][r] = bf2f(Dtj[idx]) + bf2f(Dti[idx]);
    }
  }
  __syncthreads();  // all reads of Dt_i complete before any wave stores
#pragma unroll
  for (int u = 0; u < 2; ++u) {
    const int cb = w + 8 * u;
    f32x4 acc = {0.f, 0.f, 0.f, 0.f};
#pragma unroll
    for (int kb = 0; kb < 8; ++kb) {
      union { u16 s[8]; bf16x8 f; } bv;
#pragma unroll
      for (int e = 0; e < 8; ++e)
        bv.s[e] = Dtj[(size_t)(kb * 32 + lq * 8 + e) * 256 + cb * 16 + lr];
      acc = mfma16(ad[kb], bv.f, acc);
    }
#pragma unroll
    for (int r = 0; r < 4; ++r) {
      size_t idx = (size_t)(rb * 16 + lq * 4 + r) * 256 + cb * 16 + lr;
      Dti[idx] = f2bf(acc[r] + oldv[u][r]);
    }
  }
}

// ---------------- phase C: parallel per-chunk readout ----------------------
// Grid dim3(16,128): blockIdx.x = d1b, blockIdx.y = c.  Prologue assembles
// W_start = W0 + W0@Dex + Qex (exclusive prefix = slot c-1), then runs the
// verified R5 chunk body once (P1 -> P2' -> P4a with g-add), no W update.
__global__ __launch_bounds__(512) void phaseC_kernel(
    const u16* __restrict__ tr, const u16* __restrict__ st,
    const u16* __restrict__ AG, const u16* __restrict__ LbG,
    const u16* __restrict__ Dt, const u16* __restrict__ Qb,
    const float* __restrict__ Wttt, float* __restrict__ out) {
  __shared__ u16 RpL[CC][16 * RP];
  __shared__ u16 DpL[CC][16 * RP];
  __shared__ u16 WbL[16][268];

  const int tid = threadIdx.x;
  const int lane = tid & 63;
  const int w = tid >> 6;
  const int d1b = blockIdx.x;
  const int c = blockIdx.y;
  const int lr = lane & 15;
  const int lq = lane >> 4;

  // ---- prologue: WbL = bf16(W0 + W0@Dex + Qex) ----
  {
    bf16x8 wf[8];
#pragma unroll
    for (int kb = 0; kb < 8; ++kb) {
      const float* wp = Wttt + (size_t)(d1b * 16 + lr) * 256 + kb * 32 + lq * 8;
      float4 w0 = *(const float4*)(wp);
      float4 w1 = *(const float4*)(wp + 4);
      union { u16 s[8]; bf16x8 f; } cv;
      cv.s[0] = f2bf(w0.x); cv.s[1] = f2bf(w0.y);
      cv.s[2] = f2bf(w0.z); cv.s[3] = f2bf(w0.w);
      cv.s[4] = f2bf(w1.x); cv.s[5] = f2bf(w1.y);
      cv.s[6] = f2bf(w1.z); cv.s[7] = f2bf(w1.w);
      wf[kb] = cv.f;
    }
    const size_t ex = (size_t)(c - 1) * SLOT;
#pragma unroll
    for (int u = 0; u < 2; ++u) {
      const int cb = w + 8 * u;
      f32x4 acc = {0.f, 0.f, 0.f, 0.f};
      if (c > 0) {
#pragma unroll
        for (int kb = 0; kb < 8; ++kb) {
          bf16x8 bf = ldfrag(Dt + ex + (size_t)(cb * 16 + lr) * 256 + kb * 32 + lq * 8);
          acc = mfma16(wf[kb], bf, acc);
        }
      }
#pragma unroll
      for (int r = 0; r < 4; ++r) {
        size_t ri = (size_t)(d1b * 16 + lq * 4 + r) * 256 + cb * 16 + lr;
        float v = Wttt[ri] + acc[r];
        if (c > 0) v += bf2f(Qb[ex + (size_t)(d1b * 16 + lq * 4 + r) * 256 + cb * 16 + lr]);
        WbL[lq * 4 + r][cb * 16 + lr] = f2bf(v);
      }
    }
  }
  __syncthreads();

  // ---- prefetch AG frags for both t's ----
  uint4 agR[2][8];
#pragma unroll
  for (int u = 0; u < 2; ++u) {
    const u16* ag = AG + ((size_t)(c * 16 + w + 8 * u) * 8) * 512 + lr * 32 + lq * 8;
#pragma unroll
    for (int sp = 0; sp < 8; ++sp) agR[u][sp] = *(const uint4*)(ag + sp * 512);
  }
  // ---- P1 loads ----
  uint4 trR[2][8], stR[2][8];
  float sub[2][4];
#pragma unroll
  for (int u = 0; u < 2; ++u) {
    const size_t T = (size_t)c * CC + w + 8 * u;
    const u16* trt = tr + (T * 16 + lr) * 256 + lq * 8;
    const u16* stt = st + (T * 16 + lr) * 256 + lq * 8;
#pragma unroll
    for (int k = 0; k < 8; ++k) {
      trR[u][k] = *(const uint4*)(trt + k * 32);
      stR[u][k] = *(const uint4*)(stt + k * 32);
    }
#pragma unroll
    for (int r = 0; r < 4; ++r)
      sub[u][r] = bf2f(st[(T * 16 + lq * 4 + r) * 256 + d1b * 16 + lr]);
  }

  // ---- P1: rhs = tr@W^T - st ; q = st@W^T ----
  f32x4 rhsF[2], qF[2];
#pragma unroll
  for (int u = 0; u < 2; ++u) {
    f32x4 racc = {0.f, 0.f, 0.f, 0.f}, qacc = {0.f, 0.f, 0.f, 0.f};
#pragma unroll
    for (int k = 0; k < 8; ++k) {
      bf16x8 wb = ldfrag(&WbL[lr][k * 32 + lq * 8]);
      racc = mfma16(asfrag(trR[u][k]), wb, racc);
      qacc = mfma16(asfrag(stR[u][k]), wb, qacc);
    }
#pragma unroll
    for (int r = 0; r < 4; ++r) racc[r] -= sub[u][r];
    rhsF[u] = racc; qF[u] = qacc;
    ushort4 pk;
    pk.x = f2bf(racc.x); pk.y = f2bf(racc.y);
    pk.z = f2bf(racc.z); pk.w = f2bf(racc.w);
    *(ushort4*)(&RpL[w + 8 * u][lr * RP + lq * 4]) = pk;
  }
  __syncthreads();  // b1

  // ---- LbG frags ----
  uint4 lbR[2][8];
#pragma unroll
  for (int u = 0; u < 2; ++u) {
    const u16* lb = LbG + ((size_t)(c * 16 + w + 8 * u) * 8) * 512 + lr * 32 + lq * 8;
#pragma unroll
    for (int sp = 0; sp < 8; ++sp) lbR[u][sp] = *(const uint4*)(lb + sp * 512);
  }

  // ---- P2': z = A @ rhs ; Dp = -k*(rhs - k*z) ----
#pragma unroll
  for (int u = 0; u < 2; ++u) {
    f32x4 acc = {0.f, 0.f, 0.f, 0.f};
#pragma unroll
    for (int sp = 0; sp < 8; ++sp) {
      bf16x8 bf = ldfrag(&RpL[2 * sp + (lq >> 1)][lr * RP + (lq & 1) * 8]);
      acc = mfma16(asfrag(agR[u][sp]), bf, acc);
    }
    ushort4 pk;
#pragma unroll
    for (int r = 0; r < 4; ++r) {
      float dv = rhsF[u][r] - KAPPA * acc[r];
      ((u16*)&pk)[r] = f2bf(-KAPPA * dv);
    }
    *(ushort4*)(&DpL[w + 8 * u][lr * RP + lq * 4]) = pk;
  }
  __syncthreads();  // b2

  // ---- P4: Out = g + q + Lb @ Dp ----
  float gp[2][4];
#pragma unroll
  for (int u = 0; u < 2; ++u) {
    const size_t T = (size_t)c * CC + w + 8 * u;
#pragma unroll
    for (int r = 0; r < 4; ++r)
      gp[u][r] = out[((size_t)(lq * 4 + r) * SS + T) * SD + d1b * 16 + lr];
  }
#pragma unroll
  for (int u = 0; u < 2; ++u) {
    const size_t T = (size_t)c * CC + w + 8 * u;
    f32x4 acc = qF[u];
#pragma unroll
    for (int sp = 0; sp < 8; ++sp) {
      bf16x8 bf = ldfrag(&DpL[2 * sp + (lq >> 1)][lr * RP + (lq & 1) * 8]);
      acc = mfma16(asfrag(lbR[u][sp]), bf, acc);
    }
#pragma unroll
    for (int r = 0; r < 4; ++r) {
      size_t oi = ((size_t)(lq * 4 + r) * SS + T) * SD + d1b * 16 + lr;
      out[oi] = acc[r] + gp[u][r];
    }
  }
}

extern "C" void kernel_launch(void* const* d_in, const int* in_sizes, int n_in,
                              void* d_out, int out_size, void* d_ws, size_t ws_size,
                              hipStream_t stream) {
  const float* x     = (const float*)d_in[0];
  const float* noise = (const float*)d_in[1];
  const float* a1    = (const float*)d_in[2];
  const float* a2    = (const float*)d_in[3];
  const float* Wttt  = (const float*)d_in[4];
  const float* Wproj = (const float*)d_in[5];
  const float* ffa   = (const float*)d_in[6];
  const float* ffb   = (const float*)d_in[7];
  const float* ffg   = (const float*)d_in[8];
  const float* ffe   = (const float*)d_in[9];
  float* out = (float*)d_out;

  const size_t N = (size_t)SB * SS * SD;   // 8388608 elements
  u16* tr  = (u16*)d_ws;
  u16* st  = tr + N;
  u16* trT = st + N;
  u16* AG  = trT + N;
  u16* LbG = AG + N;
  u16* Dt  = LbG + N;   // 128 slots x 65536 bf16 (transposed D)
  u16* Qb  = Dt + N;    // 128 slots x 65536 bf16 (normal Q)
  // total ws usage = 7N * 2B ~ 117.4 MB

  prep_kernel<<<8192, 256, 0, stream>>>(x, noise, a1, tr, st, trT);
  gram2ff_kernel<<<4096, 256, 0, stream>>>(tr, st, AG, LbG,
                                           x, a2, Wproj, ffa, ffb, ffg, ffe, out);
  phaseA_kernel<<<dim3(16, 128), 512, 0, stream>>>(tr, st, trT, AG, Dt, Qb);
  for (int lev = 1; lev <= 7; ++lev) {
    kq_kernel<<<1024, 512, 0, stream>>>(Dt, Qb, lev);
    kd_kernel<<<1024, 512, 0, stream>>>(Dt, lev);
  }
  phaseC_kernel<<<dim3(16, 128), 512, 0, stream>>>(tr, st, AG, LbG, Dt, Qb,
                                                   Wttt, out);
}